// Round 1
// baseline (13527.319 us; speedup 1.0000x reference)
//
#include <hip/hip_runtime.h>

#define L_ 18
#define H_ 1024
#define NH_ 8
#define HD_ 256
#define FF_ 4096
#define HOR_ 50
#define PRE_ 968
#define B_ 8
#define AD_ 32
#define TPAD_ 1024   // padded KV length (968 prefix + 50 suffix + 6 pad)
#define MROWS_ 400   // B*HOR
#define MPAD_ 512
#define QROWS_ 64    // padded query rows per (b,h)

typedef float f32x4 __attribute__((ext_vector_type(4)));
typedef short s16x4 __attribute__((ext_vector_type(4)));

__device__ __forceinline__ unsigned short f2bf(float f) {
  unsigned u = __float_as_uint(f);
  u += 0x7FFFu + ((u >> 16) & 1u);   // RTNE (inputs finite)
  return (unsigned short)(u >> 16);
}
__device__ __forceinline__ float bf2f(unsigned short h) {
  return __uint_as_float(((unsigned)h) << 16);
}
__device__ __forceinline__ float wave_max(float v) {
#pragma unroll
  for (int o = 32; o > 0; o >>= 1) v = fmaxf(v, __shfl_xor(v, o));
  return v;
}
__device__ __forceinline__ float wave_sum(float v) {
#pragma unroll
  for (int o = 32; o > 0; o >>= 1) v += __shfl_xor(v, o);
  return v;
}

// ---------------------------------------------------------------- time embedding
__global__ __launch_bounds__(256) void emb_k(const float* __restrict__ ts, float* __restrict__ emb) {
  int b = blockIdx.x, tid = threadIdx.x;
  float t = ts[b];
  for (int j = tid; j < 512; j += 256) {
    // 2*pi/period = (2*pi/0.004) * 1000^(-j/511)
    float ang = 1570.7963267948966f * expf((float)j * (-6.907755278982137f / 511.0f)) * t;
    emb[(size_t)b * H_ + j] = sinf(ang);
    emb[(size_t)b * H_ + 512 + j] = cosf(ang);
  }
}

// ---------------------------------------------------------------- [8,1024]@[1024,1024] (+bias,+silu)
__global__ __launch_bounds__(256) void gemm8_k(const float* __restrict__ A8, const float* __restrict__ W,
                                               const float* __restrict__ bias, float* __restrict__ out,
                                               int act) {
  __shared__ float a_s[8 * 1024];
  __shared__ float red[4][8][64];
  int tid = threadIdx.x;
  for (int i = tid; i < 8 * 1024; i += 256) a_s[i] = A8[i];
  __syncthreads();
  int nl = tid & 63, kg = tid >> 6;
  int n = blockIdx.x * 64 + nl;
  float acc[8];
#pragma unroll
  for (int m = 0; m < 8; m++) acc[m] = 0.f;
  for (int k = kg * 256; k < kg * 256 + 256; k++) {
    float wv = W[(size_t)k * 1024 + n];
#pragma unroll
    for (int m = 0; m < 8; m++) acc[m] += a_s[m * 1024 + k] * wv;
  }
#pragma unroll
  for (int m = 0; m < 8; m++) red[kg][m][nl] = acc[m];
  __syncthreads();
  if (kg == 0) {
#pragma unroll
    for (int m = 0; m < 8; m++) {
      float v = red[0][m][nl] + red[1][m][nl] + red[2][m][nl] + red[3][m][nl];
      if (bias) v += bias[n];
      if (act) v = v / (1.f + expf(-v));   // silu
      out[(size_t)m * 1024 + n] = v;
    }
  }
}

// ---------------------------------------------------------------- all 72 adaLN cond GEMMs in one grid
__global__ __launch_bounds__(256) void gates_k(const float* __restrict__ cond,
                                               const float* __restrict__ w0, const float* __restrict__ w1,
                                               const float* __restrict__ w2, const float* __restrict__ w3,
                                               float* __restrict__ gates) {
  __shared__ float a_s[8 * 1024];
  __shared__ float red[4][8][64];
  int tid = threadIdx.x;
  for (int i = tid; i < 8 * 1024; i += 256) a_s[i] = cond[i];
  __syncthreads();
  int z = blockIdx.z, layer = blockIdx.y;
  const float* W = (z == 0 ? w0 : z == 1 ? w1 : z == 2 ? w2 : w3) + (size_t)layer * H_ * H_;
  float* out = gates + ((size_t)(z * L_ + layer) * 8) * H_;
  int nl = tid & 63, kg = tid >> 6;
  int n = blockIdx.x * 64 + nl;
  float acc[8];
#pragma unroll
  for (int m = 0; m < 8; m++) acc[m] = 0.f;
  for (int k = kg * 256; k < kg * 256 + 256; k++) {
    float wv = W[(size_t)k * 1024 + n];
#pragma unroll
    for (int m = 0; m < 8; m++) acc[m] += a_s[m * 1024 + k] * wv;
  }
#pragma unroll
  for (int m = 0; m < 8; m++) red[kg][m][nl] = acc[m];
  __syncthreads();
  if (kg == 0) {
#pragma unroll
    for (int m = 0; m < 8; m++)
      out[(size_t)m * 1024 + n] = red[0][m][nl] + red[1][m][nl] + red[2][m][nl] + red[3][m][nl];
  }
}

// ---------------------------------------------------------------- pad-mask -> per-batch valid counts
// Handles bool(1B) or int32(4B) encodings: int32 all-ones has nonzero bytes only at i%4==0.
__global__ void offs_k(const unsigned char* __restrict__ mask, int* __restrict__ offs) {
  __shared__ int cnt[8];
  __shared__ int mod4;
  int tid = threadIdx.x;
  if (tid < 8) cnt[tid] = 0;
  if (tid == 8) mod4 = 0;
  __syncthreads();
  for (int i = tid; i < B_ * PRE_; i += 256) {
    unsigned char v = mask[i];
    if (v) {
      atomicAdd(&cnt[i / PRE_], 1);
      if (i & 3) atomicAdd(&mod4, 1);
    }
  }
  __syncthreads();
  if (tid < 8) offs[tid] = (mod4 == 0) ? cnt[tid] * 4 : cnt[tid];
}

// ---------------------------------------------------------------- h = x_t @ action_in_w + b  (pad rows = 0)
__global__ __launch_bounds__(256) void action_in_k(const float* __restrict__ xt, const float* __restrict__ Wi,
                                                   const float* __restrict__ bi, float* __restrict__ h) {
  int idx = blockIdx.x * 256 + threadIdx.x;   // over MPAD_*H_
  int m = idx >> 10, n = idx & 1023;
  float v = 0.f;
  if (m < MROWS_) {
    const float* xr = xt + (size_t)m * AD_;
#pragma unroll
    for (int k = 0; k < AD_; k++) v += xr[k] * Wi[(size_t)k * H_ + n];
    v += bi[n];
  }
  h[idx] = v;
}

// ---------------------------------------------------------------- AdaRMSNorm -> bf16 (pad rows = 0)
__global__ __launch_bounds__(256) void ada_k(const float* __restrict__ X, const float* __restrict__ nw,
                                             const float* __restrict__ sc, unsigned short* __restrict__ Y) {
  int m = blockIdx.x, tid = threadIdx.x;
  size_t base = (size_t)m * H_;
  if (m >= MROWS_) {
#pragma unroll
    for (int j = 0; j < 4; j++) Y[base + tid * 4 + j] = 0;
    return;
  }
  f32x4 x = *(const f32x4*)(X + base + tid * 4);
  float ss = x[0] * x[0] + x[1] * x[1] + x[2] * x[2] + x[3] * x[3];
  __shared__ float r4[4];
  float wsv = wave_sum(ss);
  if ((tid & 63) == 0) r4[tid >> 6] = wsv;
  __syncthreads();
  float rs = rsqrtf((r4[0] + r4[1] + r4[2] + r4[3]) * (1.f / 1024.f) + 1e-6f);
  int b = m / HOR_;
#pragma unroll
  for (int j = 0; j < 4; j++) {
    int n = tid * 4 + j;
    Y[base + n] = f2bf(x[j] * rs * (1.f + nw[n]) * (1.f + sc[(size_t)b * H_ + n]));
  }
}

// ---------------------------------------------------------------- main MFMA GEMM: C = A(bf16)[MPAD,K] @ W(f32)[K,N]
enum { GM_BF16 = 0, GM_F32 = 1, GM_GELUMUL = 2, GM_RESID = 3 };

template <int MODE>
__global__ __launch_bounds__(256) void gemm_k(const unsigned short* __restrict__ A, const float* __restrict__ W,
                                              int K, int N, void* __restrict__ out,
                                              const float* __restrict__ aux,   // GELUMUL: u[MPAD,N]; RESID: prev[MPAD,N]
                                              const float* __restrict__ gate)  // RESID: [B_,N]
{
  const int tid = threadIdx.x;
  const int wv = tid >> 6, l = tid & 63;
  const int lr = l & 15, lk = ((l >> 4) << 2);
  const int m0 = blockIdx.x * 128 + wv * 32;
  const int n0 = blockIdx.y * 64;

  f32x4 acc[2][4];
#pragma unroll
  for (int a = 0; a < 2; a++)
#pragma unroll
    for (int b = 0; b < 4; b++) acc[a][b] = (f32x4){0.f, 0.f, 0.f, 0.f};

  for (int k0 = 0; k0 < K; k0 += 16) {
    s16x4 av[2];
#pragma unroll
    for (int mf = 0; mf < 2; mf++)
      av[mf] = *(const s16x4*)(A + (size_t)(m0 + mf * 16 + lr) * K + (k0 + lk));
#pragma unroll
    for (int nf = 0; nf < 4; nf++) {
      const float* wp = W + (size_t)(k0 + lk) * N + (n0 + nf * 16 + lr);
      unsigned short b0 = f2bf(wp[0]);
      unsigned short b1 = f2bf(wp[(size_t)N]);
      unsigned short b2 = f2bf(wp[(size_t)2 * N]);
      unsigned short b3 = f2bf(wp[(size_t)3 * N]);
      union { s16x4 v; unsigned u[2]; } bb;
      bb.u[0] = (unsigned)b0 | ((unsigned)b1 << 16);
      bb.u[1] = (unsigned)b2 | ((unsigned)b3 << 16);
#pragma unroll
      for (int mf = 0; mf < 2; mf++)
        acc[mf][nf] = __builtin_amdgcn_mfma_f32_16x16x16bf16_1k(av[mf], bb.v, acc[mf][nf], 0, 0, 0);
    }
  }

#pragma unroll
  for (int mf = 0; mf < 2; mf++)
#pragma unroll
    for (int nf = 0; nf < 4; nf++)
#pragma unroll
      for (int r = 0; r < 4; r++) {
        int row = m0 + mf * 16 + lk + r;
        int col = n0 + nf * 16 + lr;
        size_t idx = (size_t)row * N + col;
        float v = acc[mf][nf][r];
        if (MODE == GM_BF16) {
          ((unsigned short*)out)[idx] = f2bf(v);
        } else if (MODE == GM_F32) {
          ((float*)out)[idx] = v;
        } else if (MODE == GM_GELUMUL) {
          float g = 0.5f * v * (1.f + tanhf(0.7978845608028654f * (v + 0.044715f * v * v * v)));
          ((unsigned short*)out)[idx] = f2bf(g * aux[idx]);
        } else {  // GM_RESID
          float o = 0.f;
          if (row < MROWS_) {
            int b = row / HOR_;
            o = aux[idx] + gate[(size_t)b * N + col] * v;
          }
          ((float*)out)[idx] = o;
        }
      }
}

// ---------------------------------------------------------------- prefix KV f32 -> bf16 (+ zero tail pad)
__global__ __launch_bounds__(256) void prefix_k(const float* __restrict__ pk, const float* __restrict__ pv,
                                                int layer, unsigned short* __restrict__ Kf,
                                                unsigned short* __restrict__ Vf) {
  int t = blockIdx.x, b = blockIdx.y, d = threadIdx.x;
  size_t dst = ((size_t)b * TPAD_ + t) * HD_ + d;
  if (t < PRE_) {
    size_t src = (((size_t)b * L_ + layer) * PRE_ + t) * HD_ + d;
    Kf[dst] = f2bf(pk[src]);
    Vf[dst] = f2bf(pv[src]);
  } else if (t >= PRE_ + HOR_) {
    Kf[dst] = 0;
    Vf[dst] = 0;
  }
}

// ---------------------------------------------------------------- RoPE(q,k) + scatter to attn layouts; copy v
__global__ __launch_bounds__(256) void rope_k(const unsigned short* __restrict__ qlin,
                                              const unsigned short* __restrict__ klin,
                                              const unsigned short* __restrict__ vlin,
                                              const int* __restrict__ offs,
                                              unsigned short* __restrict__ qr,
                                              unsigned short* __restrict__ Kf,
                                              unsigned short* __restrict__ Vf) {
  int s = blockIdx.x, b = blockIdx.y, tid = threadIdx.x;
  int m = b * HOR_ + s;
  float pos = (float)(offs[b] + s);
#pragma unroll
  for (int it = 0; it < 4; it++) {
    int p = tid + it * 256;          // 1024 rope pairs across 8 heads
    int h = p >> 7, dd = p & 127;
    float inv = expf((float)dd * (-9.210340371976184f / 128.0f));  // 10000^(-dd/128)
    float a = pos * inv;
    float c = cosf(a), sn = sinf(a);
    const unsigned short* qp = qlin + (size_t)m * 2048 + h * HD_;
    float x1 = bf2f(qp[dd]), x2 = bf2f(qp[dd + 128]);
    unsigned short* qo = qr + (((size_t)(b * NH_ + h)) * QROWS_ + s) * HD_;
    qo[dd] = f2bf(x1 * c - x2 * sn);
    qo[dd + 128] = f2bf(x2 * c + x1 * sn);
  }
  if (tid < 128) {
    int dd = tid;
    float inv = expf((float)dd * (-9.210340371976184f / 128.0f));
    float a = pos * inv;
    float c = cosf(a), sn = sinf(a);
    const unsigned short* kp = klin + (size_t)m * HD_;
    float x1 = bf2f(kp[dd]), x2 = bf2f(kp[dd + 128]);
    unsigned short* ko = Kf + ((size_t)b * TPAD_ + PRE_ + s) * HD_;
    ko[dd] = f2bf(x1 * c - x2 * sn);
    ko[dd + 128] = f2bf(x2 * c + x1 * sn);
  }
  Vf[((size_t)b * TPAD_ + PRE_ + s) * HD_ + tid] = vlin[(size_t)m * HD_ + tid];
}

// ---------------------------------------------------------------- S = scale*Q@K^T + mask
__global__ __launch_bounds__(256) void scores_k(const unsigned short* __restrict__ qr,
                                                const unsigned short* __restrict__ Kf,
                                                float* __restrict__ S) {
  int tid = threadIdx.x;
  int wv = tid >> 6, l = tid & 63;
  int lr = l & 15, lk = ((l >> 4) << 2);
  int t0 = blockIdx.x * 64;
  int h = blockIdx.y, b = blockIdx.z;
  int mrow0 = wv * 16;
  const unsigned short* qbase = qr + (((size_t)(b * NH_ + h)) * QROWS_ + mrow0 + lr) * HD_;
  f32x4 acc[4];
#pragma unroll
  for (int nf = 0; nf < 4; nf++) acc[nf] = (f32x4){0.f, 0.f, 0.f, 0.f};
  for (int k0 = 0; k0 < HD_; k0 += 16) {
    s16x4 av = *(const s16x4*)(qbase + k0 + lk);
#pragma unroll
    for (int nf = 0; nf < 4; nf++) {
      int t = t0 + nf * 16 + lr;
      s16x4 bv = *(const s16x4*)(Kf + ((size_t)b * TPAD_ + t) * HD_ + k0 + lk);
      acc[nf] = __builtin_amdgcn_mfma_f32_16x16x16bf16_1k(av, bv, acc[nf], 0, 0, 0);
    }
  }
#pragma unroll
  for (int nf = 0; nf < 4; nf++)
#pragma unroll
    for (int r = 0; r < 4; r++) {
      int row = mrow0 + lk + r;
      int t = t0 + nf * 16 + lr;
      float v = acc[nf][r] * 0.0625f;               // 256^-0.5
      if (t >= PRE_ && (t - PRE_) > row) v += -1e9f; // causal suffix + tail pad
      S[(((size_t)(b * NH_ + h)) * QROWS_ + row) * TPAD_ + t] = v;
    }
}

// ---------------------------------------------------------------- row softmax -> P (bf16, pad cols zeroed)
__global__ __launch_bounds__(256) void softmax_k(const float* __restrict__ S, unsigned short* __restrict__ P) {
  int m = blockIdx.x, h = blockIdx.y, b = blockIdx.z;
  size_t base = (((size_t)(b * NH_ + h)) * QROWS_ + m) * TPAD_;
  int tid = threadIdx.x;
  float vals[4];
  float mx = -3.0e38f;
#pragma unroll
  for (int i = 0; i < 4; i++) {
    int t = tid + i * 256;
    vals[i] = (t < PRE_ + HOR_) ? S[base + t] : -3.0e38f;
    mx = fmaxf(mx, vals[i]);
  }
  __shared__ float r4[4];
  float wm = wave_max(mx);
  if ((tid & 63) == 0) r4[tid >> 6] = wm;
  __syncthreads();
  mx = fmaxf(fmaxf(r4[0], r4[1]), fmaxf(r4[2], r4[3]));
  __syncthreads();
  float s = 0.f;
#pragma unroll
  for (int i = 0; i < 4; i++) {
    int t = tid + i * 256;
    float e = (t < PRE_ + HOR_) ? expf(vals[i] - mx) : 0.f;
    vals[i] = e;
    s += e;
  }
  float wsv = wave_sum(s);
  if ((tid & 63) == 0) r4[tid >> 6] = wsv;
  __syncthreads();
  float inv = 1.f / (r4[0] + r4[1] + r4[2] + r4[3]);
#pragma unroll
  for (int i = 0; i < 4; i++) {
    int t = tid + i * 256;
    P[base + t] = (t < PRE_ + HOR_) ? f2bf(vals[i] * inv) : (unsigned short)0;
  }
}

// ---------------------------------------------------------------- att = P @ V
__global__ __launch_bounds__(256) void pv_k(const unsigned short* __restrict__ P,
                                            const unsigned short* __restrict__ Vf,
                                            unsigned short* __restrict__ att) {
  int tid = threadIdx.x;
  int wv = tid >> 6, l = tid & 63;
  int lr = l & 15, lk = ((l >> 4) << 2);
  int n0 = blockIdx.x * 64;
  int h = blockIdx.y, b = blockIdx.z;
  int mrow0 = wv * 16;
  const unsigned short* pbase = P + (((size_t)(b * NH_ + h)) * QROWS_ + mrow0 + lr) * TPAD_;
  f32x4 acc[4];
#pragma unroll
  for (int nf = 0; nf < 4; nf++) acc[nf] = (f32x4){0.f, 0.f, 0.f, 0.f};
  for (int k0 = 0; k0 < TPAD_; k0 += 16) {
    s16x4 av = *(const s16x4*)(pbase + k0 + lk);
    const unsigned short* vp0 = Vf + ((size_t)b * TPAD_ + k0 + lk) * HD_;
#pragma unroll
    for (int nf = 0; nf < 4; nf++) {
      const unsigned short* vp = vp0 + n0 + nf * 16 + lr;
      union { s16x4 v; unsigned u[2]; } bb;
      bb.u[0] = (unsigned)vp[0] | ((unsigned)vp[HD_] << 16);
      bb.u[1] = (unsigned)vp[2 * HD_] | ((unsigned)vp[3 * HD_] << 16);
      acc[nf] = __builtin_amdgcn_mfma_f32_16x16x16bf16_1k(av, bb.v, acc[nf], 0, 0, 0);
    }
  }
#pragma unroll
  for (int nf = 0; nf < 4; nf++)
#pragma unroll
    for (int r = 0; r < 4; r++) {
      int row = mrow0 + lk + r;
      if (row < HOR_) {
        int col = n0 + nf * 16 + lr;
        att[((size_t)(b * HOR_ + row)) * 2048 + h * HD_ + col] = f2bf(acc[nf][r]);
      }
    }
}

// ---------------------------------------------------------------- out = normedF @ action_out_w + b
__global__ __launch_bounds__(256) void fout_k(const unsigned short* __restrict__ nf, const float* __restrict__ Wo,
                                              const float* __restrict__ bo, float* __restrict__ out) {
  int m = blockIdx.x, tid = threadIdx.x;
  int n = tid & 31, kg = tid >> 5;   // 8 k-groups of 128
  float acc = 0.f;
  for (int k = kg * 128; k < kg * 128 + 128; k++)
    acc += bf2f(nf[(size_t)m * H_ + k]) * Wo[(size_t)k * AD_ + n];
  __shared__ float red[8][32];
  red[kg][n] = acc;
  __syncthreads();
  if (kg == 0) {
    float v = 0.f;
#pragma unroll
    for (int g = 0; g < 8; g++) v += red[g][n];
    out[(size_t)m * AD_ + n] = v + bo[n];
  }
}

// ================================================================ host
extern "C" void kernel_launch(void* const* d_in, const int* in_sizes, int n_in,
                              void* d_out, int out_size, void* d_ws, size_t ws_size,
                              hipStream_t stream) {
  const float* prefix_keys   = (const float*)d_in[0];
  const float* prefix_values = (const float*)d_in[1];
  const float* x_t           = (const float*)d_in[2];
  const float* timestep      = (const float*)d_in[3];
  const unsigned char* pad_mask = (const unsigned char*)d_in[4];
  const float* action_in_w   = (const float*)d_in[5];
  const float* action_in_b   = (const float*)d_in[6];
  const float* action_out_w  = (const float*)d_in[7];
  const float* action_out_b  = (const float*)d_in[8];
  const float* tmlp_in_w     = (const float*)d_in[9];
  const float* tmlp_in_b     = (const float*)d_in[10];
  const float* tmlp_out_w    = (const float*)d_in[11];
  const float* tmlp_out_b    = (const float*)d_in[12];
  const float* w_q    = (const float*)d_in[13];
  const float* w_k    = (const float*)d_in[14];
  const float* w_v    = (const float*)d_in[15];
  const float* w_o    = (const float*)d_in[16];
  const float* w_gate = (const float*)d_in[17];
  const float* w_up   = (const float*)d_in[18];
  const float* w_down = (const float*)d_in[19];
  const float* in_norm_w    = (const float*)d_in[20];
  const float* in_scale_w   = (const float*)d_in[21];
  const float* in_gate_w    = (const float*)d_in[22];
  const float* post_norm_w  = (const float*)d_in[23];
  const float* post_scale_w = (const float*)d_in[24];
  const float* post_gate_w  = (const float*)d_in[25];
  const float* fnorm_w       = (const float*)d_in[26];
  const float* fnorm_scale_w = (const float*)d_in[27];

  char* wsp = (char*)d_ws;
  auto alloc = [&](size_t bytes) { void* p = (void*)wsp; wsp += (bytes + 255) & ~(size_t)255; return p; };

  float* emb0   = (float*)alloc((size_t)8 * H_ * 4);
  float* emb1   = (float*)alloc((size_t)8 * H_ * 4);
  float* cond   = (float*)alloc((size_t)8 * H_ * 4);
  float* fscale = (float*)alloc((size_t)8 * H_ * 4);
  float* gates  = (float*)alloc((size_t)4 * L_ * 8 * H_ * 4);
  int*   offs   = (int*)alloc(64);
  float* hbuf   = (float*)alloc((size_t)MPAD_ * H_ * 4);
  float* h1buf  = (float*)alloc((size_t)MPAD_ * H_ * 4);
  unsigned short* normed  = (unsigned short*)alloc((size_t)MPAD_ * H_ * 2);
  unsigned short* normed2 = (unsigned short*)alloc((size_t)MPAD_ * H_ * 2);
  unsigned short* q_lin   = (unsigned short*)alloc((size_t)MPAD_ * 2048 * 2);
  unsigned short* k_lin   = (unsigned short*)alloc((size_t)MPAD_ * HD_ * 2);
  unsigned short* v_lin   = (unsigned short*)alloc((size_t)MPAD_ * HD_ * 2);
  unsigned short* q_r     = (unsigned short*)alloc((size_t)B_ * NH_ * QROWS_ * HD_ * 2);
  unsigned short* K_full  = (unsigned short*)alloc((size_t)B_ * TPAD_ * HD_ * 2);
  unsigned short* V_full  = (unsigned short*)alloc((size_t)B_ * TPAD_ * HD_ * 2);
  float*          scoresb = (float*)alloc((size_t)B_ * NH_ * QROWS_ * TPAD_ * 4);
  unsigned short* Pbuf    = (unsigned short*)alloc((size_t)B_ * NH_ * QROWS_ * TPAD_ * 2);
  unsigned short* attb    = (unsigned short*)alloc((size_t)MPAD_ * 2048 * 2);
  float*          u_buf   = (float*)alloc((size_t)MPAD_ * FF_ * 4);
  unsigned short* t_buf   = (unsigned short*)alloc((size_t)MPAD_ * FF_ * 2);
  unsigned short* normedF = (unsigned short*)alloc((size_t)MPAD_ * H_ * 2);

  emb_k<<<8, 256, 0, stream>>>(timestep, emb0);
  gemm8_k<<<16, 256, 0, stream>>>(emb0, tmlp_in_w, tmlp_in_b, emb1, 1);
  gemm8_k<<<16, 256, 0, stream>>>(emb1, tmlp_out_w, tmlp_out_b, cond, 1);
  gemm8_k<<<16, 256, 0, stream>>>(cond, fnorm_scale_w, nullptr, fscale, 0);
  gates_k<<<dim3(16, L_, 4), 256, 0, stream>>>(cond, in_scale_w, in_gate_w, post_scale_w, post_gate_w, gates);
  offs_k<<<1, 256, 0, stream>>>(pad_mask, offs);
  action_in_k<<<(MPAD_ * H_) / 256, 256, 0, stream>>>(x_t, action_in_w, action_in_b, hbuf);

  for (int i = 0; i < L_; i++) {
    const float* wq_i = w_q + (size_t)i * H_ * 2048;
    const float* wk_i = w_k + (size_t)i * H_ * HD_;
    const float* wv_i = w_v + (size_t)i * H_ * HD_;
    const float* wo_i = w_o + (size_t)i * 2048 * H_;
    const float* wg_i = w_gate + (size_t)i * H_ * FF_;
    const float* wu_i = w_up + (size_t)i * H_ * FF_;
    const float* wd_i = w_down + (size_t)i * FF_ * H_;
    const float* g_in_scale   = gates + ((size_t)(0 * L_ + i) * 8) * H_;
    const float* g_in_gate    = gates + ((size_t)(1 * L_ + i) * 8) * H_;
    const float* g_post_scale = gates + ((size_t)(2 * L_ + i) * 8) * H_;
    const float* g_post_gate  = gates + ((size_t)(3 * L_ + i) * 8) * H_;

    ada_k<<<MPAD_, 256, 0, stream>>>(hbuf, in_norm_w + (size_t)i * H_, g_in_scale, normed);
    gemm_k<GM_BF16><<<dim3(4, 32), 256, 0, stream>>>(normed, wq_i, H_, 2048, q_lin, nullptr, nullptr);
    gemm_k<GM_BF16><<<dim3(4, 4), 256, 0, stream>>>(normed, wk_i, H_, HD_, k_lin, nullptr, nullptr);
    gemm_k<GM_BF16><<<dim3(4, 4), 256, 0, stream>>>(normed, wv_i, H_, HD_, v_lin, nullptr, nullptr);
    prefix_k<<<dim3(TPAD_, B_), 256, 0, stream>>>(prefix_keys, prefix_values, i, K_full, V_full);
    rope_k<<<dim3(HOR_, B_), 256, 0, stream>>>(q_lin, k_lin, v_lin, offs, q_r, K_full, V_full);
    scores_k<<<dim3(16, NH_, B_), 256, 0, stream>>>(q_r, K_full, scoresb);
    softmax_k<<<dim3(HOR_, NH_, B_), 256, 0, stream>>>(scoresb, Pbuf);
    pv_k<<<dim3(4, NH_, B_), 256, 0, stream>>>(Pbuf, V_full, attb);
    gemm_k<GM_RESID><<<dim3(4, 16), 256, 0, stream>>>(attb, wo_i, 2048, H_, h1buf, hbuf, g_in_gate);
    ada_k<<<MPAD_, 256, 0, stream>>>(h1buf, post_norm_w + (size_t)i * H_, g_post_scale, normed2);
    gemm_k<GM_F32><<<dim3(4, 64), 256, 0, stream>>>(normed2, wu_i, H_, FF_, u_buf, nullptr, nullptr);
    gemm_k<GM_GELUMUL><<<dim3(4, 64), 256, 0, stream>>>(normed2, wg_i, H_, FF_, t_buf, u_buf, nullptr);
    gemm_k<GM_RESID><<<dim3(4, 16), 256, 0, stream>>>(t_buf, wd_i, FF_, H_, hbuf, h1buf, g_post_gate);
  }

  ada_k<<<MPAD_, 256, 0, stream>>>(hbuf, fnorm_w, fscale, normedF);
  fout_k<<<MROWS_, 256, 0, stream>>>(normedF, action_out_w, action_out_b, (float*)d_out);
}

// Round 2
// 9039.731 us; speedup vs baseline: 1.4964x; 1.4964x over previous
//
#include <hip/hip_runtime.h>

#define L_ 18
#define H_ 1024
#define NH_ 8
#define HD_ 256
#define FF_ 4096
#define HOR_ 50
#define PRE_ 968
#define B_ 8
#define AD_ 32
#define TPAD_ 1024   // padded KV length (968 prefix + 50 suffix + 6 pad)
#define MROWS_ 400   // B*HOR
#define MPAD_ 512
#define QROWS_ 64    // padded query rows per (b,h)

typedef float f32x4 __attribute__((ext_vector_type(4)));
typedef short s16x4 __attribute__((ext_vector_type(4)));
typedef unsigned short u16x8 __attribute__((ext_vector_type(8)));

__device__ __forceinline__ unsigned short f2bf(float f) {
  unsigned u = __float_as_uint(f);
  u += 0x7FFFu + ((u >> 16) & 1u);   // RTNE (inputs finite)
  return (unsigned short)(u >> 16);
}
__device__ __forceinline__ float bf2f(unsigned short h) {
  return __uint_as_float(((unsigned)h) << 16);
}
__device__ __forceinline__ float wave_max(float v) {
#pragma unroll
  for (int o = 32; o > 0; o >>= 1) v = fmaxf(v, __shfl_xor(v, o));
  return v;
}
__device__ __forceinline__ float wave_sum(float v) {
#pragma unroll
  for (int o = 32; o > 0; o >>= 1) v += __shfl_xor(v, o);
  return v;
}

// ---------------------------------------------------------------- time embedding
__global__ __launch_bounds__(256) void emb_k(const float* __restrict__ ts, float* __restrict__ emb) {
  int b = blockIdx.x, tid = threadIdx.x;
  float t = ts[b];
  for (int j = tid; j < 512; j += 256) {
    float ang = 1570.7963267948966f * expf((float)j * (-6.907755278982137f / 511.0f)) * t;
    emb[(size_t)b * H_ + j] = sinf(ang);
    emb[(size_t)b * H_ + 512 + j] = cosf(ang);
  }
}

// ---------------------------------------------------------------- [8,1024]@[1024,1024] (+bias,+silu)
__global__ __launch_bounds__(256) void gemm8_k(const float* __restrict__ A8, const float* __restrict__ W,
                                               const float* __restrict__ bias, float* __restrict__ out,
                                               int act) {
  __shared__ float a_s[8 * 1024];
  __shared__ float red[4][8][64];
  int tid = threadIdx.x;
  for (int i = tid; i < 8 * 1024; i += 256) a_s[i] = A8[i];
  __syncthreads();
  int nl = tid & 63, kg = tid >> 6;
  int n = blockIdx.x * 64 + nl;
  float acc[8];
#pragma unroll
  for (int m = 0; m < 8; m++) acc[m] = 0.f;
  for (int k = kg * 256; k < kg * 256 + 256; k++) {
    float wv = W[(size_t)k * 1024 + n];
#pragma unroll
    for (int m = 0; m < 8; m++) acc[m] += a_s[m * 1024 + k] * wv;
  }
#pragma unroll
  for (int m = 0; m < 8; m++) red[kg][m][nl] = acc[m];
  __syncthreads();
  if (kg == 0) {
#pragma unroll
    for (int m = 0; m < 8; m++) {
      float v = red[0][m][nl] + red[1][m][nl] + red[2][m][nl] + red[3][m][nl];
      if (bias) v += bias[n];
      if (act) v = v / (1.f + expf(-v));
      out[(size_t)m * 1024 + n] = v;
    }
  }
}

// ---------------------------------------------------------------- all 72 adaLN cond GEMMs in one grid
__global__ __launch_bounds__(256) void gates_k(const float* __restrict__ cond,
                                               const float* __restrict__ w0, const float* __restrict__ w1,
                                               const float* __restrict__ w2, const float* __restrict__ w3,
                                               float* __restrict__ gates) {
  __shared__ float a_s[8 * 1024];
  __shared__ float red[4][8][64];
  int tid = threadIdx.x;
  for (int i = tid; i < 8 * 1024; i += 256) a_s[i] = cond[i];
  __syncthreads();
  int z = blockIdx.z, layer = blockIdx.y;
  const float* W = (z == 0 ? w0 : z == 1 ? w1 : z == 2 ? w2 : w3) + (size_t)layer * H_ * H_;
  float* out = gates + ((size_t)(z * L_ + layer) * 8) * H_;
  int nl = tid & 63, kg = tid >> 6;
  int n = blockIdx.x * 64 + nl;
  float acc[8];
#pragma unroll
  for (int m = 0; m < 8; m++) acc[m] = 0.f;
  for (int k = kg * 256; k < kg * 256 + 256; k++) {
    float wv = W[(size_t)k * 1024 + n];
#pragma unroll
    for (int m = 0; m < 8; m++) acc[m] += a_s[m * 1024 + k] * wv;
  }
#pragma unroll
  for (int m = 0; m < 8; m++) red[kg][m][nl] = acc[m];
  __syncthreads();
  if (kg == 0) {
#pragma unroll
    for (int m = 0; m < 8; m++)
      out[(size_t)m * 1024 + n] = red[0][m][nl] + red[1][m][nl] + red[2][m][nl] + red[3][m][nl];
  }
}

// ---------------------------------------------------------------- pad-mask -> per-batch valid counts
__global__ void offs_k(const unsigned char* __restrict__ mask, int* __restrict__ offs) {
  __shared__ int cnt[8];
  __shared__ int mod4;
  int tid = threadIdx.x;
  if (tid < 8) cnt[tid] = 0;
  if (tid == 8) mod4 = 0;
  __syncthreads();
  for (int i = tid; i < B_ * PRE_; i += 256) {
    unsigned char v = mask[i];
    if (v) {
      atomicAdd(&cnt[i / PRE_], 1);
      if (i & 3) atomicAdd(&mod4, 1);
    }
  }
  __syncthreads();
  if (tid < 8) offs[tid] = (mod4 == 0) ? cnt[tid] * 4 : cnt[tid];
}

// ---------------------------------------------------------------- h = x_t @ action_in_w + b  (pad rows = 0)
__global__ __launch_bounds__(256) void action_in_k(const float* __restrict__ xt, const float* __restrict__ Wi,
                                                   const float* __restrict__ bi, float* __restrict__ h) {
  int idx = blockIdx.x * 256 + threadIdx.x;
  int m = idx >> 10, n = idx & 1023;
  float v = 0.f;
  if (m < MROWS_) {
    const float* xr = xt + (size_t)m * AD_;
#pragma unroll
    for (int k = 0; k < AD_; k++) v += xr[k] * Wi[(size_t)k * H_ + n];
    v += bi[n];
  }
  h[idx] = v;
}

// ---------------------------------------------------------------- AdaRMSNorm -> bf16 (pad rows = 0)
__global__ __launch_bounds__(256) void ada_k(const float* __restrict__ X, const float* __restrict__ nw,
                                             const float* __restrict__ sc, unsigned short* __restrict__ Y) {
  int m = blockIdx.x, tid = threadIdx.x;
  size_t base = (size_t)m * H_;
  if (m >= MROWS_) {
#pragma unroll
    for (int j = 0; j < 4; j++) Y[base + tid * 4 + j] = 0;
    return;
  }
  f32x4 x = *(const f32x4*)(X + base + tid * 4);
  float ss = x[0] * x[0] + x[1] * x[1] + x[2] * x[2] + x[3] * x[3];
  __shared__ float r4[4];
  float wsv = wave_sum(ss);
  if ((tid & 63) == 0) r4[tid >> 6] = wsv;
  __syncthreads();
  float rs = rsqrtf((r4[0] + r4[1] + r4[2] + r4[3]) * (1.f / 1024.f) + 1e-6f);
  int b = m / HOR_;
#pragma unroll
  for (int j = 0; j < 4; j++) {
    int n = tid * 4 + j;
    Y[base + n] = f2bf(x[j] * rs * (1.f + nw[n]) * (1.f + sc[(size_t)b * H_ + n]));
  }
}

// ================================================================ unified double-buffered MFMA GEMM
// A bf16 [512][Ksz], W f32 [Ksz][ldw] staged to LDS (bf16, transposed, padded stride).
// MF=4: tall (wave=64 rows, block=512 rows, grid.x = N/64).  MF=1: wave=16 rows, grid.y = m-split (128 rows/block).
// MODE 0=QKV(out bf16 stride 2560, W in {wq,wk,wv}), 1=UPGATE(blockIdx.z selects gate/up; gelu on gate),
//      2=RESID(out f32 = aux + gate*acc, pad rows 0). AMUL: A-fragment = A ⊙ A2 (down GEMM reads gelu(g)·u).
#define KSTEP_ 128
#define WTS_ 140    // LDS row stride (shorts): 2-way-max read banks, 8B aligned

template <int MF, int MODE, bool AMUL>
__global__ __launch_bounds__(512) void gemmU_k(const unsigned short* __restrict__ A,
                                               const unsigned short* __restrict__ A2, int lda,
                                               const float* __restrict__ W0, const float* __restrict__ W1,
                                               const float* __restrict__ W2, int Ksz,
                                               void* __restrict__ out0, void* __restrict__ out1,
                                               const float* __restrict__ aux, const float* __restrict__ gatev) {
  const int tid = threadIdx.x;
  const int wv = tid >> 6, l = tid & 63;
  const int lr = l & 15, lk = ((l >> 4) << 2);
  const int n0 = blockIdx.x * 64;
  const int m0 = (MF == 4) ? wv * 64 : (int)blockIdx.y * 128 + wv * 16;

  const float* W;
  int ldw;
  int wcol;
  if (MODE == 0) {
    if (n0 < 2048)      { W = W0; ldw = 2048; wcol = n0; }
    else if (n0 < 2304) { W = W1; ldw = 256;  wcol = n0 - 2048; }
    else                { W = W2; ldw = 256;  wcol = n0 - 2304; }
  } else if (MODE == 1) {
    W = blockIdx.z ? W1 : W0; ldw = 4096; wcol = n0;
  } else {
    W = W0; ldw = 1024; wcol = n0;
  }

  __shared__ unsigned short Wt[2][64][WTS_];
  const int sc = (tid & 15) * 4;      // n within strip
  const int sr = (tid >> 4) * 2;      // k-pair base within 64-half

  f32x4 acc[MF][4];
#pragma unroll
  for (int a = 0; a < MF; a++)
#pragma unroll
    for (int b = 0; b < 4; b++) acc[a][b] = (f32x4){0.f, 0.f, 0.f, 0.f};

  const int niter = Ksz / KSTEP_;
  f32x4 p[4];

#define LOADW(IT)                                                                              \
  {                                                                                            \
    int kb_ = (IT) * KSTEP_;                                                                   \
    _Pragma("unroll") for (int h_ = 0; h_ < 2; h_++) _Pragma("unroll") for (int jj_ = 0; jj_ < 2; jj_++) \
        p[2 * h_ + jj_] = *(const f32x4*)(W + (size_t)(kb_ + h_ * 64 + sr + jj_) * ldw + wcol + sc); \
  }
#define STOREW(BUF)                                                                            \
  {                                                                                            \
    _Pragma("unroll") for (int h_ = 0; h_ < 2; h_++) _Pragma("unroll") for (int j_ = 0; j_ < 4; j_++) { \
      unsigned lo_ = f2bf(p[2 * h_ + 0][j_]);                                                  \
      unsigned hi_ = f2bf(p[2 * h_ + 1][j_]);                                                  \
      *(unsigned*)&Wt[BUF][sc + j_][h_ * 64 + sr] = lo_ | (hi_ << 16);                         \
    }                                                                                          \
  }

  LOADW(0);
  STOREW(0);
  __syncthreads();

  for (int it = 0; it < niter; ++it) {
    if (it + 1 < niter) LOADW(it + 1);
    const int cur = it & 1;
    const int kb = it * KSTEP_;
#pragma unroll
    for (int s = 0; s < 8; s++) {
      s16x4 bfr[4];
#pragma unroll
      for (int nf = 0; nf < 4; nf++) bfr[nf] = *(const s16x4*)&Wt[cur][nf * 16 + lr][s * 16 + lk];
#pragma unroll
      for (int mf = 0; mf < MF; mf++) {
        size_t aoff = (size_t)(m0 + mf * 16 + lr) * lda + kb + s * 16 + lk;
        s16x4 a = *(const s16x4*)(A + aoff);
        if (AMUL) {
          s16x4 u = *(const s16x4*)(A2 + aoff);
          s16x4 r;
#pragma unroll
          for (int j = 0; j < 4; j++)
            r[j] = (short)f2bf(bf2f((unsigned short)a[j]) * bf2f((unsigned short)u[j]));
          a = r;
        }
#pragma unroll
        for (int nf = 0; nf < 4; nf++)
          acc[mf][nf] = __builtin_amdgcn_mfma_f32_16x16x16bf16_1k(a, bfr[nf], acc[mf][nf], 0, 0, 0);
      }
    }
    if (it + 1 < niter) STOREW((it + 1) & 1);
    __syncthreads();
  }
#undef LOADW
#undef STOREW

  // epilogue
#pragma unroll
  for (int mf = 0; mf < MF; mf++)
#pragma unroll
    for (int nf = 0; nf < 4; nf++)
#pragma unroll
      for (int r = 0; r < 4; r++) {
        int row = m0 + mf * 16 + lk + r;
        int col = n0 + nf * 16 + lr;
        float v = acc[mf][nf][r];
        if (MODE == 0) {
          ((unsigned short*)out0)[(size_t)row * 2560 + col] = f2bf(v);
        } else if (MODE == 1) {
          unsigned short* o = (unsigned short*)(blockIdx.z ? out1 : out0);
          if (blockIdx.z == 0)
            v = 0.5f * v * (1.f + tanhf(0.7978845608028654f * (v + 0.044715f * v * v * v)));
          o[(size_t)row * 4096 + col] = f2bf(v);
        } else {
          float o = 0.f;
          if (row < MROWS_) {
            int b = row / HOR_;
            o = aux[(size_t)row * 1024 + col] + gatev[(size_t)b * 1024 + col] * v;
          }
          ((float*)out0)[(size_t)row * 1024 + col] = o;
        }
      }
}

// ---------------------------------------------------------------- prefix: K f32->bf16 row-major; V f32->bf16 transposed [b][d][t]
__global__ __launch_bounds__(256) void prefixT_k(const float* __restrict__ pk, const float* __restrict__ pv,
                                                 int layer, unsigned short* __restrict__ Kf,
                                                 unsigned short* __restrict__ Vt) {
  int b = blockIdx.y, t0 = blockIdx.x * 64, tid = threadIdx.x;
  __shared__ unsigned short vt[256][72];
  const float* kp = pk + ((size_t)(b * L_ + layer)) * PRE_ * HD_;
  const float* vp = pv + ((size_t)(b * L_ + layer)) * PRE_ * HD_;
  for (int i = 0; i < 64; i++) {
    int t = t0 + i;
    float kv = 0.f, vv = 0.f;
    if (t < PRE_) {
      kv = kp[(size_t)t * HD_ + tid];
      vv = vp[(size_t)t * HD_ + tid];
    }
    Kf[((size_t)b * TPAD_ + t) * HD_ + tid] = f2bf(kv);  // suffix rows overwritten by rope_k after
    vt[tid][i] = f2bf(vv);
  }
  __syncthreads();
#pragma unroll
  for (int p = 0; p < 4; p++) {
    int d = p * 64 + (tid >> 2);
    int c0 = (tid & 3) * 16;
    u16x8 v0, v1;
#pragma unroll
    for (int j = 0; j < 8; j++) { v0[j] = vt[d][c0 + j]; v1[j] = vt[d][c0 + 8 + j]; }
    size_t dst = ((size_t)(b * HD_ + d)) * TPAD_ + t0 + c0;
    *(u16x8*)(Vt + dst) = v0;
    *(u16x8*)(Vt + dst + 8) = v1;
  }
}

// ---------------------------------------------------------------- RoPE(q,k) from fused qkv + scatter; v -> Vt columns
__global__ __launch_bounds__(256) void rope2_k(const unsigned short* __restrict__ qkv,
                                               const int* __restrict__ offs,
                                               unsigned short* __restrict__ qr,
                                               unsigned short* __restrict__ Kf,
                                               unsigned short* __restrict__ Vt) {
  int s = blockIdx.x, b = blockIdx.y, tid = threadIdx.x;
  int m = b * HOR_ + s;
  float pos = (float)(offs[b] + s);
  const unsigned short* row = qkv + (size_t)m * 2560;
#pragma unroll
  for (int it = 0; it < 4; it++) {
    int p = tid + it * 256;          // 1024 rope pairs across 8 heads
    int h = p >> 7, dd = p & 127;
    float inv = expf((float)dd * (-9.210340371976184f / 128.0f));
    float a = pos * inv;
    float c = cosf(a), sn = sinf(a);
    const unsigned short* qp = row + h * HD_;
    float x1 = bf2f(qp[dd]), x2 = bf2f(qp[dd + 128]);
    unsigned short* qo = qr + (((size_t)(b * NH_ + h)) * QROWS_ + s) * HD_;
    qo[dd] = f2bf(x1 * c - x2 * sn);
    qo[dd + 128] = f2bf(x2 * c + x1 * sn);
  }
  if (tid < 128) {
    int dd = tid;
    float inv = expf((float)dd * (-9.210340371976184f / 128.0f));
    float a = pos * inv;
    float c = cosf(a), sn = sinf(a);
    const unsigned short* kp = row + 2048;
    float x1 = bf2f(kp[dd]), x2 = bf2f(kp[dd + 128]);
    unsigned short* ko = Kf + ((size_t)b * TPAD_ + PRE_ + s) * HD_;
    ko[dd] = f2bf(x1 * c - x2 * sn);
    ko[dd + 128] = f2bf(x2 * c + x1 * sn);
  }
  Vt[((size_t)(b * HD_ + tid)) * TPAD_ + PRE_ + s] = row[2304 + tid];
}

// ---------------------------------------------------------------- S = scale*Q@K^T + mask
__global__ __launch_bounds__(256) void scores_k(const unsigned short* __restrict__ qr,
                                                const unsigned short* __restrict__ Kf,
                                                float* __restrict__ S) {
  int tid = threadIdx.x;
  int wv = tid >> 6, l = tid & 63;
  int lr = l & 15, lk = ((l >> 4) << 2);
  int t0 = blockIdx.x * 64;
  int h = blockIdx.y, b = blockIdx.z;
  int mrow0 = wv * 16;
  const unsigned short* qbase = qr + (((size_t)(b * NH_ + h)) * QROWS_ + mrow0 + lr) * HD_;
  f32x4 acc[4];
#pragma unroll
  for (int nf = 0; nf < 4; nf++) acc[nf] = (f32x4){0.f, 0.f, 0.f, 0.f};
  for (int k0 = 0; k0 < HD_; k0 += 16) {
    s16x4 av = *(const s16x4*)(qbase + k0 + lk);
#pragma unroll
    for (int nf = 0; nf < 4; nf++) {
      int t = t0 + nf * 16 + lr;
      s16x4 bv = *(const s16x4*)(Kf + ((size_t)b * TPAD_ + t) * HD_ + k0 + lk);
      acc[nf] = __builtin_amdgcn_mfma_f32_16x16x16bf16_1k(av, bv, acc[nf], 0, 0, 0);
    }
  }
#pragma unroll
  for (int nf = 0; nf < 4; nf++)
#pragma unroll
    for (int r = 0; r < 4; r++) {
      int row = mrow0 + lk + r;
      int t = t0 + nf * 16 + lr;
      float v = acc[nf][r] * 0.0625f;
      if (t >= PRE_ && (t - PRE_) > row) v += -1e9f;
      S[(((size_t)(b * NH_ + h)) * QROWS_ + row) * TPAD_ + t] = v;
    }
}

// ---------------------------------------------------------------- row softmax -> P (bf16, pad cols zeroed)
__global__ __launch_bounds__(256) void softmax_k(const float* __restrict__ S, unsigned short* __restrict__ P) {
  int m = blockIdx.x, h = blockIdx.y, b = blockIdx.z;
  size_t base = (((size_t)(b * NH_ + h)) * QROWS_ + m) * TPAD_;
  int tid = threadIdx.x;
  float vals[4];
  float mx = -3.0e38f;
#pragma unroll
  for (int i = 0; i < 4; i++) {
    int t = tid + i * 256;
    vals[i] = (t < PRE_ + HOR_) ? S[base + t] : -3.0e38f;
    mx = fmaxf(mx, vals[i]);
  }
  __shared__ float r4[4];
  float wm = wave_max(mx);
  if ((tid & 63) == 0) r4[tid >> 6] = wm;
  __syncthreads();
  mx = fmaxf(fmaxf(r4[0], r4[1]), fmaxf(r4[2], r4[3]));
  __syncthreads();
  float s = 0.f;
#pragma unroll
  for (int i = 0; i < 4; i++) {
    int t = tid + i * 256;
    float e = (t < PRE_ + HOR_) ? expf(vals[i] - mx) : 0.f;
    vals[i] = e;
    s += e;
  }
  float wsv = wave_sum(s);
  if ((tid & 63) == 0) r4[tid >> 6] = wsv;
  __syncthreads();
  float inv = 1.f / (r4[0] + r4[1] + r4[2] + r4[3]);
#pragma unroll
  for (int i = 0; i < 4; i++) {
    int t = tid + i * 256;
    P[base + t] = (t < PRE_ + HOR_) ? f2bf(vals[i] * inv) : (unsigned short)0;
  }
}

// ---------------------------------------------------------------- att = P @ V  (B-operand from Vt, vectorized)
__global__ __launch_bounds__(256) void pv2_k(const unsigned short* __restrict__ P,
                                             const unsigned short* __restrict__ Vt,
                                             unsigned short* __restrict__ att) {
  int tid = threadIdx.x;
  int wv = tid >> 6, l = tid & 63;
  int lr = l & 15, lk = ((l >> 4) << 2);
  int h = blockIdx.x, b = blockIdx.y;
  int d0 = wv * 64;
  const unsigned short* pbase = P + (((size_t)(b * NH_ + h)) * QROWS_) * TPAD_;
  f32x4 acc[4][4];
#pragma unroll
  for (int a = 0; a < 4; a++)
#pragma unroll
    for (int c = 0; c < 4; c++) acc[a][c] = (f32x4){0.f, 0.f, 0.f, 0.f};
  for (int k0 = 0; k0 < TPAD_; k0 += 16) {
    s16x4 av[4];
#pragma unroll
    for (int mf = 0; mf < 4; mf++)
      av[mf] = *(const s16x4*)(pbase + (size_t)(mf * 16 + lr) * TPAD_ + k0 + lk);
#pragma unroll
    for (int nf = 0; nf < 4; nf++) {
      s16x4 bv = *(const s16x4*)(Vt + ((size_t)(b * HD_ + d0 + nf * 16 + lr)) * TPAD_ + k0 + lk);
#pragma unroll
      for (int mf = 0; mf < 4; mf++)
        acc[mf][nf] = __builtin_amdgcn_mfma_f32_16x16x16bf16_1k(av[mf], bv, acc[mf][nf], 0, 0, 0);
    }
  }
#pragma unroll
  for (int mf = 0; mf < 4; mf++)
#pragma unroll
    for (int nf = 0; nf < 4; nf++)
#pragma unroll
      for (int r = 0; r < 4; r++) {
        int row = mf * 16 + lk + r;
        if (row < HOR_) {
          int col = d0 + nf * 16 + lr;
          att[((size_t)(b * HOR_ + row)) * 2048 + h * HD_ + col] = f2bf(acc[mf][nf][r]);
        }
      }
}

// ---------------------------------------------------------------- out = normedF @ action_out_w + b
__global__ __launch_bounds__(256) void fout_k(const unsigned short* __restrict__ nf, const float* __restrict__ Wo,
                                              const float* __restrict__ bo, float* __restrict__ out) {
  int m = blockIdx.x, tid = threadIdx.x;
  int n = tid & 31, kg = tid >> 5;
  float acc = 0.f;
  for (int k = kg * 128; k < kg * 128 + 128; k++)
    acc += bf2f(nf[(size_t)m * H_ + k]) * Wo[(size_t)k * AD_ + n];
  __shared__ float red[8][32];
  red[kg][n] = acc;
  __syncthreads();
  if (kg == 0) {
    float v = 0.f;
#pragma unroll
    for (int g = 0; g < 8; g++) v += red[g][n];
    out[(size_t)m * AD_ + n] = v + bo[n];
  }
}

// ================================================================ host
extern "C" void kernel_launch(void* const* d_in, const int* in_sizes, int n_in,
                              void* d_out, int out_size, void* d_ws, size_t ws_size,
                              hipStream_t stream) {
  const float* prefix_keys   = (const float*)d_in[0];
  const float* prefix_values = (const float*)d_in[1];
  const float* x_t           = (const float*)d_in[2];
  const float* timestep      = (const float*)d_in[3];
  const unsigned char* pad_mask = (const unsigned char*)d_in[4];
  const float* action_in_w   = (const float*)d_in[5];
  const float* action_in_b   = (const float*)d_in[6];
  const float* action_out_w  = (const float*)d_in[7];
  const float* action_out_b  = (const float*)d_in[8];
  const float* tmlp_in_w     = (const float*)d_in[9];
  const float* tmlp_in_b     = (const float*)d_in[10];
  const float* tmlp_out_w    = (const float*)d_in[11];
  const float* tmlp_out_b    = (const float*)d_in[12];
  const float* w_q    = (const float*)d_in[13];
  const float* w_k    = (const float*)d_in[14];
  const float* w_v    = (const float*)d_in[15];
  const float* w_o    = (const float*)d_in[16];
  const float* w_gate = (const float*)d_in[17];
  const float* w_up   = (const float*)d_in[18];
  const float* w_down = (const float*)d_in[19];
  const float* in_norm_w    = (const float*)d_in[20];
  const float* in_scale_w   = (const float*)d_in[21];
  const float* in_gate_w    = (const float*)d_in[22];
  const float* post_norm_w  = (const float*)d_in[23];
  const float* post_scale_w = (const float*)d_in[24];
  const float* post_gate_w  = (const float*)d_in[25];
  const float* fnorm_w       = (const float*)d_in[26];
  const float* fnorm_scale_w = (const float*)d_in[27];

  char* wsp = (char*)d_ws;
  auto alloc = [&](size_t bytes) { void* p = (void*)wsp; wsp += (bytes + 255) & ~(size_t)255; return p; };

  float* emb0   = (float*)alloc((size_t)8 * H_ * 4);
  float* emb1   = (float*)alloc((size_t)8 * H_ * 4);
  float* cond   = (float*)alloc((size_t)8 * H_ * 4);
  float* fscale = (float*)alloc((size_t)8 * H_ * 4);
  float* gates  = (float*)alloc((size_t)4 * L_ * 8 * H_ * 4);
  int*   offs   = (int*)alloc(64);
  float* hbuf   = (float*)alloc((size_t)MPAD_ * H_ * 4);
  float* h1buf  = (float*)alloc((size_t)MPAD_ * H_ * 4);
  unsigned short* normed  = (unsigned short*)alloc((size_t)MPAD_ * H_ * 2);
  unsigned short* normed2 = (unsigned short*)alloc((size_t)MPAD_ * H_ * 2);
  unsigned short* qkv     = (unsigned short*)alloc((size_t)MPAD_ * 2560 * 2);
  unsigned short* q_r     = (unsigned short*)alloc((size_t)B_ * NH_ * QROWS_ * HD_ * 2);
  unsigned short* K_full  = (unsigned short*)alloc((size_t)B_ * TPAD_ * HD_ * 2);
  unsigned short* Vt      = (unsigned short*)alloc((size_t)B_ * HD_ * TPAD_ * 2);
  float*          scoresb = (float*)alloc((size_t)B_ * NH_ * QROWS_ * TPAD_ * 4);
  unsigned short* Pbuf    = (unsigned short*)alloc((size_t)B_ * NH_ * QROWS_ * TPAD_ * 2);
  unsigned short* attb    = (unsigned short*)alloc((size_t)MPAD_ * 2048 * 2);
  unsigned short* g_buf   = (unsigned short*)alloc((size_t)MPAD_ * FF_ * 2);
  unsigned short* u_buf   = (unsigned short*)alloc((size_t)MPAD_ * FF_ * 2);
  unsigned short* normedF = (unsigned short*)alloc((size_t)MPAD_ * H_ * 2);

  // attb pad rows (400..511) are never written by pv2_k: zero them once per call
  hipMemsetAsync(attb + (size_t)MROWS_ * 2048, 0, (size_t)(MPAD_ - MROWS_) * 2048 * 2, stream);

  emb_k<<<8, 256, 0, stream>>>(timestep, emb0);
  gemm8_k<<<16, 256, 0, stream>>>(emb0, tmlp_in_w, tmlp_in_b, emb1, 1);
  gemm8_k<<<16, 256, 0, stream>>>(emb1, tmlp_out_w, tmlp_out_b, cond, 1);
  gemm8_k<<<16, 256, 0, stream>>>(cond, fnorm_scale_w, nullptr, fscale, 0);
  gates_k<<<dim3(16, L_, 4), 256, 0, stream>>>(cond, in_scale_w, in_gate_w, post_scale_w, post_gate_w, gates);
  offs_k<<<1, 256, 0, stream>>>(pad_mask, offs);
  action_in_k<<<(MPAD_ * H_) / 256, 256, 0, stream>>>(x_t, action_in_w, action_in_b, hbuf);

  for (int i = 0; i < L_; i++) {
    const float* wq_i = w_q + (size_t)i * H_ * 2048;
    const float* wk_i = w_k + (size_t)i * H_ * HD_;
    const float* wv_i = w_v + (size_t)i * H_ * HD_;
    const float* wo_i = w_o + (size_t)i * 2048 * H_;
    const float* wg_i = w_gate + (size_t)i * H_ * FF_;
    const float* wu_i = w_up + (size_t)i * H_ * FF_;
    const float* wd_i = w_down + (size_t)i * FF_ * H_;
    const float* g_in_scale   = gates + ((size_t)(0 * L_ + i) * 8) * H_;
    const float* g_in_gate    = gates + ((size_t)(1 * L_ + i) * 8) * H_;
    const float* g_post_scale = gates + ((size_t)(2 * L_ + i) * 8) * H_;
    const float* g_post_gate  = gates + ((size_t)(3 * L_ + i) * 8) * H_;

    ada_k<<<MPAD_, 256, 0, stream>>>(hbuf, in_norm_w + (size_t)i * H_, g_in_scale, normed);
    gemmU_k<4, 0, false><<<dim3(40, 1, 1), 512, 0, stream>>>(normed, nullptr, H_, wq_i, wk_i, wv_i, H_,
                                                             qkv, nullptr, nullptr, nullptr);
    prefixT_k<<<dim3(16, B_), 256, 0, stream>>>(prefix_keys, prefix_values, i, K_full, Vt);
    rope2_k<<<dim3(HOR_, B_), 256, 0, stream>>>(qkv, offs, q_r, K_full, Vt);
    scores_k<<<dim3(16, NH_, B_), 256, 0, stream>>>(q_r, K_full, scoresb);
    softmax_k<<<dim3(HOR_, NH_, B_), 256, 0, stream>>>(scoresb, Pbuf);
    pv2_k<<<dim3(NH_, B_), 256, 0, stream>>>(Pbuf, Vt, attb);
    gemmU_k<1, 2, false><<<dim3(16, 4), 512, 0, stream>>>(attb, nullptr, 2048, wo_i, nullptr, nullptr, 2048,
                                                          h1buf, nullptr, hbuf, g_in_gate);
    ada_k<<<MPAD_, 256, 0, stream>>>(h1buf, post_norm_w + (size_t)i * H_, g_post_scale, normed2);
    gemmU_k<4, 1, false><<<dim3(64, 1, 2), 512, 0, stream>>>(normed2, nullptr, H_, wg_i, wu_i, nullptr, H_,
                                                             g_buf, u_buf, nullptr, nullptr);
    gemmU_k<1, 2, true><<<dim3(16, 4), 512, 0, stream>>>(g_buf, u_buf, FF_, wd_i, nullptr, nullptr, FF_,
                                                         hbuf, nullptr, h1buf, g_post_gate);
  }

  ada_k<<<MPAD_, 256, 0, stream>>>(hbuf, fnorm_w, fscale, normedF);
  fout_k<<<MROWS_, 256, 0, stream>>>(normedF, action_out_w, action_out_b, (float*)d_out);
}

// Round 3
// 5291.146 us; speedup vs baseline: 2.5566x; 1.7085x over previous
//
#include <hip/hip_runtime.h>

#define L_ 18
#define H_ 1024
#define NH_ 8
#define HD_ 256
#define FF_ 4096
#define HOR_ 50
#define PRE_ 968
#define B_ 8
#define AD_ 32
#define TPAD_ 1024   // padded KV length (968 prefix + 50 suffix + 6 pad)
#define MROWS_ 400   // B*HOR
#define MPAD_ 512
#define QROWS_ 64    // padded query rows per (b,h)

typedef float f32x4 __attribute__((ext_vector_type(4)));
typedef short s16x4 __attribute__((ext_vector_type(4)));
typedef unsigned short u16x8 __attribute__((ext_vector_type(8)));

__device__ __forceinline__ unsigned short f2bf(float f) {
  unsigned u = __float_as_uint(f);
  u += 0x7FFFu + ((u >> 16) & 1u);   // RTNE (inputs finite)
  return (unsigned short)(u >> 16);
}
__device__ __forceinline__ float bf2f(unsigned short h) {
  return __uint_as_float(((unsigned)h) << 16);
}
__device__ __forceinline__ float wave_max(float v) {
#pragma unroll
  for (int o = 32; o > 0; o >>= 1) v = fmaxf(v, __shfl_xor(v, o));
  return v;
}
__device__ __forceinline__ float wave_sum(float v) {
#pragma unroll
  for (int o = 32; o > 0; o >>= 1) v += __shfl_xor(v, o);
  return v;
}

// ---------------------------------------------------------------- time embedding
__global__ __launch_bounds__(256) void emb_k(const float* __restrict__ ts, float* __restrict__ emb) {
  int b = blockIdx.x, tid = threadIdx.x;
  float t = ts[b];
  for (int j = tid; j < 512; j += 256) {
    float ang = 1570.7963267948966f * expf((float)j * (-6.907755278982137f / 511.0f)) * t;
    emb[(size_t)b * H_ + j] = sinf(ang);
    emb[(size_t)b * H_ + 512 + j] = cosf(ang);
  }
}

// ---------------------------------------------------------------- [8,1024]@[1024,1024] (+bias,+silu)
__global__ __launch_bounds__(256) void gemm8_k(const float* __restrict__ A8, const float* __restrict__ W,
                                               const float* __restrict__ bias, float* __restrict__ out,
                                               int act) {
  __shared__ float a_s[8 * 1024];
  __shared__ float red[4][8][64];
  int tid = threadIdx.x;
  for (int i = tid; i < 8 * 1024; i += 256) a_s[i] = A8[i];
  __syncthreads();
  int nl = tid & 63, kg = tid >> 6;
  int n = blockIdx.x * 64 + nl;
  float acc[8];
#pragma unroll
  for (int m = 0; m < 8; m++) acc[m] = 0.f;
  for (int k = kg * 256; k < kg * 256 + 256; k++) {
    float wv = W[(size_t)k * 1024 + n];
#pragma unroll
    for (int m = 0; m < 8; m++) acc[m] += a_s[m * 1024 + k] * wv;
  }
#pragma unroll
  for (int m = 0; m < 8; m++) red[kg][m][nl] = acc[m];
  __syncthreads();
  if (kg == 0) {
#pragma unroll
    for (int m = 0; m < 8; m++) {
      float v = red[0][m][nl] + red[1][m][nl] + red[2][m][nl] + red[3][m][nl];
      if (bias) v += bias[n];
      if (act) v = v / (1.f + expf(-v));
      out[(size_t)m * 1024 + n] = v;
    }
  }
}

// ---------------------------------------------------------------- all 72 adaLN cond GEMMs in one grid
__global__ __launch_bounds__(256) void gates_k(const float* __restrict__ cond,
                                               const float* __restrict__ w0, const float* __restrict__ w1,
                                               const float* __restrict__ w2, const float* __restrict__ w3,
                                               float* __restrict__ gates) {
  __shared__ float a_s[8 * 1024];
  __shared__ float red[4][8][64];
  int tid = threadIdx.x;
  for (int i = tid; i < 8 * 1024; i += 256) a_s[i] = cond[i];
  __syncthreads();
  int z = blockIdx.z, layer = blockIdx.y;
  const float* W = (z == 0 ? w0 : z == 1 ? w1 : z == 2 ? w2 : w3) + (size_t)layer * H_ * H_;
  float* out = gates + ((size_t)(z * L_ + layer) * 8) * H_;
  int nl = tid & 63, kg = tid >> 6;
  int n = blockIdx.x * 64 + nl;
  float acc[8];
#pragma unroll
  for (int m = 0; m < 8; m++) acc[m] = 0.f;
  for (int k = kg * 256; k < kg * 256 + 256; k++) {
    float wv = W[(size_t)k * 1024 + n];
#pragma unroll
    for (int m = 0; m < 8; m++) acc[m] += a_s[m * 1024 + k] * wv;
  }
#pragma unroll
  for (int m = 0; m < 8; m++) red[kg][m][nl] = acc[m];
  __syncthreads();
  if (kg == 0) {
#pragma unroll
    for (int m = 0; m < 8; m++)
      out[(size_t)m * 1024 + n] = red[0][m][nl] + red[1][m][nl] + red[2][m][nl] + red[3][m][nl];
  }
}

// ---------------------------------------------------------------- pad-mask -> per-batch valid counts
__global__ void offs_k(const unsigned char* __restrict__ mask, int* __restrict__ offs) {
  __shared__ int cnt[8];
  __shared__ int mod4;
  int tid = threadIdx.x;
  if (tid < 8) cnt[tid] = 0;
  if (tid == 8) mod4 = 0;
  __syncthreads();
  for (int i = tid; i < B_ * PRE_; i += 256) {
    unsigned char v = mask[i];
    if (v) {
      atomicAdd(&cnt[i / PRE_], 1);
      if (i & 3) atomicAdd(&mod4, 1);
    }
  }
  __syncthreads();
  if (tid < 8) offs[tid] = (mod4 == 0) ? cnt[tid] * 4 : cnt[tid];
}

// ---------------------------------------------------------------- h = x_t @ action_in_w + b  (pad rows = 0)
__global__ __launch_bounds__(256) void action_in_k(const float* __restrict__ xt, const float* __restrict__ Wi,
                                                   const float* __restrict__ bi, float* __restrict__ h) {
  int idx = blockIdx.x * 256 + threadIdx.x;
  int m = idx >> 10, n = idx & 1023;
  float v = 0.f;
  if (m < MROWS_) {
    const float* xr = xt + (size_t)m * AD_;
#pragma unroll
    for (int k = 0; k < AD_; k++) v += xr[k] * Wi[(size_t)k * H_ + n];
    v += bi[n];
  }
  h[idx] = v;
}

// ---------------------------------------------------------------- AdaRMSNorm -> bf16 (pad rows = 0), layer-0 only
__global__ __launch_bounds__(256) void ada_k(const float* __restrict__ X, const float* __restrict__ nw,
                                             const float* __restrict__ sc, unsigned short* __restrict__ Y) {
  int m = blockIdx.x, tid = threadIdx.x;
  size_t base = (size_t)m * H_;
  if (m >= MROWS_) {
#pragma unroll
    for (int j = 0; j < 4; j++) Y[base + tid * 4 + j] = 0;
    return;
  }
  f32x4 x = *(const f32x4*)(X + base + tid * 4);
  float ss = x[0] * x[0] + x[1] * x[1] + x[2] * x[2] + x[3] * x[3];
  __shared__ float r4[4];
  float wsv = wave_sum(ss);
  if ((tid & 63) == 0) r4[tid >> 6] = wsv;
  __syncthreads();
  float rs = rsqrtf((r4[0] + r4[1] + r4[2] + r4[3]) * (1.f / 1024.f) + 1e-6f);
  int b = m / HOR_;
#pragma unroll
  for (int j = 0; j < 4; j++) {
    int n = tid * 4 + j;
    Y[base + n] = f2bf(x[j] * rs * (1.f + nw[n]) * (1.f + sc[(size_t)b * H_ + n]));
  }
}

// ================================================================ split-K MFMA GEMM stage 1
// A bf16 [512][lda]; W f32 [Ksz][ldw]; strip = 32 cols (MODE2: 32 gate + 32 up).
// MODE 0=QKV(Ntot 2560; W in {wq,wk,wv}), 1=WO(Ntot 1024), 2=UPGATE(dual; direct t=gelu(g)*u bf16 out),
//      3=DOWN(Ntot 1024). NS = K-split count; grid (nstrips, NS). 512 thr, wave = 64 rows x strip.
#define KSTEP_ 128
#define LST_ 132   // LDS k-stride in shorts

template <int MODE, int NS>
__global__ __launch_bounds__(512) void gemmS_k(const unsigned short* __restrict__ A, int lda, int Ksz,
                                               const float* __restrict__ W0, const float* __restrict__ W1,
                                               const float* __restrict__ W2,
                                               float* __restrict__ part, unsigned short* __restrict__ outT) {
  constexpr int NCOL = (MODE == 2) ? 64 : 32;
  constexpr int NF = NCOL / 16;
  const int tid = threadIdx.x;
  const int wv = tid >> 6, l = tid & 63;
  const int lr = l & 15, lk = (l >> 4) << 2;
  const int n0 = blockIdx.x * 32;
  const int kz = blockIdx.y;
  const int KC = Ksz / NS;
  const int kbase = kz * KC;
  const int m0 = wv * 64;

  const float* Wg;
  const float* Wu = nullptr;
  int ldw, wcol, Ntot;
  if (MODE == 0) {
    Ntot = 2560;
    if (n0 < 2048)      { Wg = W0; ldw = 2048; wcol = n0; }
    else if (n0 < 2304) { Wg = W1; ldw = 256;  wcol = n0 - 2048; }
    else                { Wg = W2; ldw = 256;  wcol = n0 - 2304; }
  } else if (MODE == 1) {
    Ntot = 1024; Wg = W0; ldw = 1024; wcol = n0;
  } else if (MODE == 2) {
    Ntot = 4096; Wg = W0; Wu = W1; ldw = 4096; wcol = n0;
  } else {
    Ntot = 1024; Wg = W0; ldw = 1024; wcol = n0;
  }

  __shared__ unsigned short Wt[2][NCOL][LST_];
  const int pr = tid >> 3;          // 0..63: k-pair index within KSTEP
  const int c0 = (tid & 7) * 4;     // col group within strip

  f32x4 acc[4][NF];
#pragma unroll
  for (int a = 0; a < 4; a++)
#pragma unroll
    for (int b = 0; b < NF; b++) acc[a][b] = (f32x4){0.f, 0.f, 0.f, 0.f};

  const int niter = KC / KSTEP_;
  f32x4 pa0, pa1, pb0, pb1;

#define LOADW(IT)                                                                     \
  {                                                                                   \
    size_t kk_ = (size_t)(kbase + (IT) * KSTEP_ + 2 * pr);                            \
    pa0 = *(const f32x4*)(Wg + kk_ * ldw + wcol + c0);                                \
    pa1 = *(const f32x4*)(Wg + (kk_ + 1) * ldw + wcol + c0);                          \
    if (MODE == 2) {                                                                  \
      pb0 = *(const f32x4*)(Wu + kk_ * ldw + wcol + c0);                              \
      pb1 = *(const f32x4*)(Wu + (kk_ + 1) * ldw + wcol + c0);                        \
    }                                                                                 \
  }
#define STOREW(BUF)                                                                   \
  {                                                                                   \
    _Pragma("unroll") for (int j_ = 0; j_ < 4; j_++) {                                \
      unsigned v_ = (unsigned)f2bf(pa0[j_]) | ((unsigned)f2bf(pa1[j_]) << 16);        \
      *(unsigned*)&Wt[BUF][c0 + j_][2 * pr] = v_;                                     \
      if (MODE == 2) {                                                                \
        unsigned u_ = (unsigned)f2bf(pb0[j_]) | ((unsigned)f2bf(pb1[j_]) << 16);      \
        *(unsigned*)&Wt[BUF][32 + c0 + j_][2 * pr] = u_;                              \
      }                                                                               \
    }                                                                                 \
  }

  LOADW(0);
  STOREW(0);
  __syncthreads();

  for (int it = 0; it < niter; ++it) {
    if (it + 1 < niter) LOADW(it + 1);
    const int cur = it & 1;
    const int kb = kbase + it * KSTEP_;
#pragma unroll
    for (int s = 0; s < 8; s++) {
      s16x4 bfr[NF];
#pragma unroll
      for (int nf = 0; nf < NF; nf++) bfr[nf] = *(const s16x4*)&Wt[cur][nf * 16 + lr][s * 16 + lk];
#pragma unroll
      for (int mf = 0; mf < 4; mf++) {
        s16x4 a = *(const s16x4*)(A + (size_t)(m0 + mf * 16 + lr) * lda + kb + s * 16 + lk);
#pragma unroll
        for (int nf = 0; nf < NF; nf++)
          acc[mf][nf] = __builtin_amdgcn_mfma_f32_16x16x16bf16_1k(a, bfr[nf], acc[mf][nf], 0, 0, 0);
      }
    }
    if (it + 1 < niter) STOREW((it + 1) & 1);
    __syncthreads();
  }
#undef LOADW
#undef STOREW

  if (MODE == 2) {
#pragma unroll
    for (int mf = 0; mf < 4; mf++)
#pragma unroll
      for (int nf = 0; nf < 2; nf++)
#pragma unroll
        for (int r = 0; r < 4; r++) {
          int row = m0 + mf * 16 + lk + r;
          int col = n0 + nf * 16 + lr;
          float g = acc[mf][nf][r];
          float u = acc[mf][nf + 2][r];
          g = 0.5f * g * (1.f + tanhf(0.7978845608028654f * (g + 0.044715f * g * g * g)));
          outT[(size_t)row * 4096 + col] = f2bf(g * u);
        }
  } else {
#pragma unroll
    for (int mf = 0; mf < 4; mf++)
#pragma unroll
      for (int nf = 0; nf < NF; nf++)
#pragma unroll
        for (int r = 0; r < 4; r++) {
          int row = m0 + mf * 16 + lk + r;
          int col = n0 + nf * 16 + lr;
          part[((size_t)kz * MPAD_ + row) * Ntot + col] = acc[mf][nf][r];
        }
  }
}

// ---------------------------------------------------------------- split-K reduce + residual-gate + AdaRMSNorm
// h = prev + gate*sum(part); outH=h (f32); outN = bf16(rms(h)*(1+nw)*(1+sc))   [pad rows -> 0]
template <int NS>
__global__ __launch_bounds__(256) void redA_k(const float* __restrict__ part, const float* __restrict__ prev,
                                              const float* __restrict__ gatev, const float* __restrict__ nw,
                                              const float* __restrict__ sc, float* __restrict__ outH,
                                              unsigned short* __restrict__ outN) {
  int r = blockIdx.x, tid = threadIdx.x;
  int c = tid * 4;
  f32x4 h = (f32x4){0.f, 0.f, 0.f, 0.f};
  int b = 0;
  if (r < MROWS_) {
    b = r / HOR_;
    f32x4 v = (f32x4){0.f, 0.f, 0.f, 0.f};
#pragma unroll
    for (int z = 0; z < NS; z++) v += *(const f32x4*)(part + ((size_t)z * MPAD_ + r) * H_ + c);
    f32x4 pv = *(const f32x4*)(prev + (size_t)r * H_ + c);
    f32x4 gv = *(const f32x4*)(gatev + (size_t)b * H_ + c);
    h = pv + gv * v;
  }
  *(f32x4*)(outH + (size_t)r * H_ + c) = h;
  float ss = h[0] * h[0] + h[1] * h[1] + h[2] * h[2] + h[3] * h[3];
  __shared__ float r4[4];
  float wsv = wave_sum(ss);
  if ((tid & 63) == 0) r4[tid >> 6] = wsv;
  __syncthreads();
  float rs = rsqrtf((r4[0] + r4[1] + r4[2] + r4[3]) * (1.f / 1024.f) + 1e-6f);
#pragma unroll
  for (int j = 0; j < 4; j++) {
    int n = c + j;
    outN[(size_t)r * H_ + n] = f2bf(h[j] * rs * (1.f + nw[n]) * (1.f + sc[(size_t)b * H_ + n]));
  }
}

// ---------------------------------------------------------------- QKV reduce + RoPE + scatter (per suffix token)
__global__ __launch_bounds__(256) void qkvRR_k(const float* __restrict__ part, const int* __restrict__ offs,
                                               unsigned short* __restrict__ qr, unsigned short* __restrict__ Kf,
                                               unsigned short* __restrict__ Vt) {
  int s = blockIdx.x, b = blockIdx.y, tid = threadIdx.x;
  if (s >= HOR_) {   // zero q_r pad rows
#pragma unroll
    for (int h = 0; h < NH_; h++) qr[(((size_t)(b * NH_ + h)) * QROWS_ + s) * HD_ + tid] = 0;
    return;
  }
  __shared__ float row[2560];
  int m = b * HOR_ + s;
#pragma unroll
  for (int i = 0; i < 10; i++) {
    int c = tid + i * 256;
    row[c] = part[((size_t)0 * MPAD_ + m) * 2560 + c] + part[((size_t)1 * MPAD_ + m) * 2560 + c];
  }
  __syncthreads();
  float pos = (float)(offs[b] + s);
#pragma unroll
  for (int it = 0; it < 4; it++) {
    int p = tid + it * 256;
    int h = p >> 7, dd = p & 127;
    float inv = expf((float)dd * (-9.210340371976184f / 128.0f));
    float a = pos * inv;
    float cc = cosf(a), sn = sinf(a);
    float x1 = row[h * HD_ + dd], x2 = row[h * HD_ + dd + 128];
    unsigned short* qo = qr + (((size_t)(b * NH_ + h)) * QROWS_ + s) * HD_;
    qo[dd] = f2bf(x1 * cc - x2 * sn);
    qo[dd + 128] = f2bf(x2 * cc + x1 * sn);
  }
  if (tid < 128) {
    int dd = tid;
    float inv = expf((float)dd * (-9.210340371976184f / 128.0f));
    float a = pos * inv;
    float cc = cosf(a), sn = sinf(a);
    float x1 = row[2048 + dd], x2 = row[2048 + dd + 128];
    unsigned short* ko = Kf + ((size_t)b * TPAD_ + PRE_ + s) * HD_;
    ko[dd] = f2bf(x1 * cc - x2 * sn);
    ko[dd + 128] = f2bf(x2 * cc + x1 * sn);
  }
  Vt[((size_t)(b * HD_ + tid)) * TPAD_ + PRE_ + s] = f2bf(row[2304 + tid]);
}

// ---------------------------------------------------------------- all-layer prefix convert: K row-major, V transposed
__global__ __launch_bounds__(256) void prefixAll_k(const float* __restrict__ pk, const float* __restrict__ pv,
                                                   unsigned short* __restrict__ Kf_all,
                                                   unsigned short* __restrict__ Vt_all) {
  int b = blockIdx.y, t0 = blockIdx.x * 64, layer = blockIdx.z, tid = threadIdx.x;
  unsigned short* Kf = Kf_all + (size_t)layer * B_ * TPAD_ * HD_;
  unsigned short* Vt = Vt_all + (size_t)layer * B_ * HD_ * TPAD_;
  __shared__ unsigned short vt[256][72];
  const float* kp = pk + ((size_t)(b * L_ + layer)) * PRE_ * HD_;
  const float* vp = pv + ((size_t)(b * L_ + layer)) * PRE_ * HD_;
  for (int i = 0; i < 64; i++) {
    int t = t0 + i;
    float kv = 0.f, vv = 0.f;
    if (t < PRE_) {
      kv = kp[(size_t)t * HD_ + tid];
      vv = vp[(size_t)t * HD_ + tid];
    }
    Kf[((size_t)b * TPAD_ + t) * HD_ + tid] = f2bf(kv);  // suffix rows overwritten by qkvRR later
    vt[tid][i] = f2bf(vv);
  }
  __syncthreads();
#pragma unroll
  for (int p = 0; p < 4; p++) {
    int d = p * 64 + (tid >> 2);
    int c0 = (tid & 3) * 16;
    u16x8 v0, v1;
#pragma unroll
    for (int j = 0; j < 8; j++) { v0[j] = vt[d][c0 + j]; v1[j] = vt[d][c0 + 8 + j]; }
    size_t dst = ((size_t)(b * HD_ + d)) * TPAD_ + t0 + c0;
    *(u16x8*)(Vt + dst) = v0;
    *(u16x8*)(Vt + dst + 8) = v1;
  }
}

// ---------------------------------------------------------------- S = scale*Q@K^T + mask
__global__ __launch_bounds__(256) void scores_k(const unsigned short* __restrict__ qr,
                                                const unsigned short* __restrict__ Kf,
                                                float* __restrict__ S) {
  int tid = threadIdx.x;
  int wv = tid >> 6, l = tid & 63;
  int lr = l & 15, lk = ((l >> 4) << 2);
  int t0 = blockIdx.x * 64;
  int h = blockIdx.y, b = blockIdx.z;
  int mrow0 = wv * 16;
  const unsigned short* qbase = qr + (((size_t)(b * NH_ + h)) * QROWS_ + mrow0 + lr) * HD_;
  f32x4 acc[4];
#pragma unroll
  for (int nf = 0; nf < 4; nf++) acc[nf] = (f32x4){0.f, 0.f, 0.f, 0.f};
  for (int k0 = 0; k0 < HD_; k0 += 16) {
    s16x4 av = *(const s16x4*)(qbase + k0 + lk);
#pragma unroll
    for (int nf = 0; nf < 4; nf++) {
      int t = t0 + nf * 16 + lr;
      s16x4 bv = *(const s16x4*)(Kf + ((size_t)b * TPAD_ + t) * HD_ + k0 + lk);
      acc[nf] = __builtin_amdgcn_mfma_f32_16x16x16bf16_1k(av, bv, acc[nf], 0, 0, 0);
    }
  }
#pragma unroll
  for (int nf = 0; nf < 4; nf++)
#pragma unroll
    for (int r = 0; r < 4; r++) {
      int row = mrow0 + lk + r;
      int t = t0 + nf * 16 + lr;
      float v = acc[nf][r] * 0.0625f;
      if (t >= PRE_ && (t - PRE_) > row) v += -1e9f;
      S[(((size_t)(b * NH_ + h)) * QROWS_ + row) * TPAD_ + t] = v;
    }
}

// ---------------------------------------------------------------- row softmax -> P (bf16, pad cols zeroed)
__global__ __launch_bounds__(256) void softmax_k(const float* __restrict__ S, unsigned short* __restrict__ P) {
  int m = blockIdx.x, h = blockIdx.y, b = blockIdx.z;
  size_t base = (((size_t)(b * NH_ + h)) * QROWS_ + m) * TPAD_;
  int tid = threadIdx.x;
  float vals[4];
  float mx = -3.0e38f;
#pragma unroll
  for (int i = 0; i < 4; i++) {
    int t = tid + i * 256;
    vals[i] = (t < PRE_ + HOR_) ? S[base + t] : -3.0e38f;
    mx = fmaxf(mx, vals[i]);
  }
  __shared__ float r4[4];
  float wm = wave_max(mx);
  if ((tid & 63) == 0) r4[tid >> 6] = wm;
  __syncthreads();
  mx = fmaxf(fmaxf(r4[0], r4[1]), fmaxf(r4[2], r4[3]));
  __syncthreads();
  float s = 0.f;
#pragma unroll
  for (int i = 0; i < 4; i++) {
    int t = tid + i * 256;
    float e = (t < PRE_ + HOR_) ? expf(vals[i] - mx) : 0.f;
    vals[i] = e;
    s += e;
  }
  float wsv = wave_sum(s);
  if ((tid & 63) == 0) r4[tid >> 6] = wsv;
  __syncthreads();
  float inv = 1.f / (r4[0] + r4[1] + r4[2] + r4[3]);
#pragma unroll
  for (int i = 0; i < 4; i++) {
    int t = tid + i * 256;
    P[base + t] = (t < PRE_ + HOR_) ? f2bf(vals[i] * inv) : (unsigned short)0;
  }
}

// ---------------------------------------------------------------- att partial = P @ V over k-chunk (split-K x4)
__global__ __launch_bounds__(256) void pvS_k(const unsigned short* __restrict__ P,
                                             const unsigned short* __restrict__ Vt,
                                             float* __restrict__ attp) {
  int tid = threadIdx.x;
  int wv = tid >> 6, l = tid & 63;
  int lr = l & 15, lk = ((l >> 4) << 2);
  int h = blockIdx.x, b = blockIdx.y, z = blockIdx.z;
  int d0 = wv * 64;
  const unsigned short* pbase = P + (((size_t)(b * NH_ + h)) * QROWS_) * TPAD_;
  f32x4 acc[4][4];
#pragma unroll
  for (int a = 0; a < 4; a++)
#pragma unroll
    for (int c = 0; c < 4; c++) acc[a][c] = (f32x4){0.f, 0.f, 0.f, 0.f};
  for (int k0 = z * 256; k0 < z * 256 + 256; k0 += 16) {
    s16x4 av[4];
#pragma unroll
    for (int mf = 0; mf < 4; mf++)
      av[mf] = *(const s16x4*)(pbase + (size_t)(mf * 16 + lr) * TPAD_ + k0 + lk);
#pragma unroll
    for (int nf = 0; nf < 4; nf++) {
      s16x4 bv = *(const s16x4*)(Vt + ((size_t)(b * HD_ + d0 + nf * 16 + lr)) * TPAD_ + k0 + lk);
#pragma unroll
      for (int mf = 0; mf < 4; mf++)
        acc[mf][nf] = __builtin_amdgcn_mfma_f32_16x16x16bf16_1k(av[mf], bv, acc[mf][nf], 0, 0, 0);
    }
  }
#pragma unroll
  for (int mf = 0; mf < 4; mf++)
#pragma unroll
    for (int nf = 0; nf < 4; nf++)
#pragma unroll
      for (int r = 0; r < 4; r++) {
        int row = mf * 16 + lk + r;
        int col = d0 + nf * 16 + lr;
        attp[(((size_t)z * 64 + b * NH_ + h) * QROWS_ + row) * HD_ + col] = acc[mf][nf][r];
      }
}

// ---------------------------------------------------------------- att reduce -> attb bf16 [512][2048], pads zeroed
__global__ __launch_bounds__(256) void attR_k(const float* __restrict__ attp, unsigned short* __restrict__ attb) {
  int gid = blockIdx.x * 256 + threadIdx.x;
  int pos = gid * 4;
  int m = pos >> 11, col = pos & 2047;
  f32x4 v = (f32x4){0.f, 0.f, 0.f, 0.f};
  if (m < MROWS_) {
    int b = m / HOR_, s = m - b * HOR_;
    int h = col >> 8, d = col & 255;
#pragma unroll
    for (int z = 0; z < 4; z++)
      v += *(const f32x4*)(attp + (((size_t)z * 64 + b * NH_ + h) * QROWS_ + s) * HD_ + d);
  }
#pragma unroll
  for (int j = 0; j < 4; j++) attb[(size_t)pos + j] = f2bf(v[j]);
}

// ---------------------------------------------------------------- out = normedF @ action_out_w + b
__global__ __launch_bounds__(256) void fout_k(const unsigned short* __restrict__ nf, const float* __restrict__ Wo,
                                              const float* __restrict__ bo, float* __restrict__ out) {
  int m = blockIdx.x, tid = threadIdx.x;
  int n = tid & 31, kg = tid >> 5;
  float acc = 0.f;
  for (int k = kg * 128; k < kg * 128 + 128; k++)
    acc += bf2f(nf[(size_t)m * H_ + k]) * Wo[(size_t)k * AD_ + n];
  __shared__ float red[8][32];
  red[kg][n] = acc;
  __syncthreads();
  if (kg == 0) {
    float v = 0.f;
#pragma unroll
    for (int g = 0; g < 8; g++) v += red[g][n];
    out[(size_t)m * AD_ + n] = v + bo[n];
  }
}

// ================================================================ host
extern "C" void kernel_launch(void* const* d_in, const int* in_sizes, int n_in,
                              void* d_out, int out_size, void* d_ws, size_t ws_size,
                              hipStream_t stream) {
  const float* prefix_keys   = (const float*)d_in[0];
  const float* prefix_values = (const float*)d_in[1];
  const float* x_t           = (const float*)d_in[2];
  const float* timestep      = (const float*)d_in[3];
  const unsigned char* pad_mask = (const unsigned char*)d_in[4];
  const float* action_in_w   = (const float*)d_in[5];
  const float* action_in_b   = (const float*)d_in[6];
  const float* action_out_w  = (const float*)d_in[7];
  const float* action_out_b  = (const float*)d_in[8];
  const float* tmlp_in_w     = (const float*)d_in[9];
  const float* tmlp_in_b     = (const float*)d_in[10];
  const float* tmlp_out_w    = (const float*)d_in[11];
  const float* tmlp_out_b    = (const float*)d_in[12];
  const float* w_q    = (const float*)d_in[13];
  const float* w_k    = (const float*)d_in[14];
  const float* w_v    = (const float*)d_in[15];
  const float* w_o    = (const float*)d_in[16];
  const float* w_gate = (const float*)d_in[17];
  const float* w_up   = (const float*)d_in[18];
  const float* w_down = (const float*)d_in[19];
  const float* in_norm_w    = (const float*)d_in[20];
  const float* in_scale_w   = (const float*)d_in[21];
  const float* in_gate_w    = (const float*)d_in[22];
  const float* post_norm_w  = (const float*)d_in[23];
  const float* post_scale_w = (const float*)d_in[24];
  const float* post_gate_w  = (const float*)d_in[25];
  const float* fnorm_w       = (const float*)d_in[26];
  const float* fnorm_scale_w = (const float*)d_in[27];

  char* wsp = (char*)d_ws;
  auto alloc = [&](size_t bytes) { void* p = (void*)wsp; wsp += (bytes + 255) & ~(size_t)255; return p; };

  float* emb0   = (float*)alloc((size_t)8 * H_ * 4);
  float* emb1   = (float*)alloc((size_t)8 * H_ * 4);
  float* cond   = (float*)alloc((size_t)8 * H_ * 4);
  float* fscale = (float*)alloc((size_t)8 * H_ * 4);
  float* gates  = (float*)alloc((size_t)4 * L_ * 8 * H_ * 4);
  int*   offs   = (int*)alloc(64);
  float* hbuf   = (float*)alloc((size_t)MPAD_ * H_ * 4);
  float* h1buf  = (float*)alloc((size_t)MPAD_ * H_ * 4);
  unsigned short* normed  = (unsigned short*)alloc((size_t)MPAD_ * H_ * 2);
  unsigned short* normed2 = (unsigned short*)alloc((size_t)MPAD_ * H_ * 2);
  unsigned short* q_r     = (unsigned short*)alloc((size_t)B_ * NH_ * QROWS_ * HD_ * 2);
  unsigned short* Kf_all  = (unsigned short*)alloc((size_t)L_ * B_ * TPAD_ * HD_ * 2);
  unsigned short* Vt_all  = (unsigned short*)alloc((size_t)L_ * B_ * HD_ * TPAD_ * 2);
  float*          scoresb = (float*)alloc((size_t)B_ * NH_ * QROWS_ * TPAD_ * 4);
  unsigned short* Pbuf    = (unsigned short*)alloc((size_t)B_ * NH_ * QROWS_ * TPAD_ * 2);
  unsigned short* attb    = (unsigned short*)alloc((size_t)MPAD_ * 2048 * 2);
  unsigned short* t_buf   = (unsigned short*)alloc((size_t)MPAD_ * FF_ * 2);
  float* qkvpart = (float*)alloc((size_t)2 * MPAD_ * 2560 * 4);
  float* wopart  = (float*)alloc((size_t)4 * MPAD_ * 1024 * 4);
  float* dpart   = (float*)alloc((size_t)8 * MPAD_ * 1024 * 4);
  float* attp    = (float*)alloc((size_t)4 * 64 * QROWS_ * HD_ * 4);

  emb_k<<<8, 256, 0, stream>>>(timestep, emb0);
  gemm8_k<<<16, 256, 0, stream>>>(emb0, tmlp_in_w, tmlp_in_b, emb1, 1);
  gemm8_k<<<16, 256, 0, stream>>>(emb1, tmlp_out_w, tmlp_out_b, cond, 1);
  gemm8_k<<<16, 256, 0, stream>>>(cond, fnorm_scale_w, nullptr, fscale, 0);
  gates_k<<<dim3(16, L_, 4), 256, 0, stream>>>(cond, in_scale_w, in_gate_w, post_scale_w, post_gate_w, gates);
  offs_k<<<1, 256, 0, stream>>>(pad_mask, offs);
  action_in_k<<<(MPAD_ * H_) / 256, 256, 0, stream>>>(x_t, action_in_w, action_in_b, hbuf);
  prefixAll_k<<<dim3(16, B_, L_), 256, 0, stream>>>(prefix_keys, prefix_values, Kf_all, Vt_all);
  ada_k<<<MPAD_, 256, 0, stream>>>(hbuf, in_norm_w, gates + 0, normed);  // layer 0 in_scale = gates[0][0]

  for (int i = 0; i < L_; i++) {
    const float* wq_i = w_q + (size_t)i * H_ * 2048;
    const float* wk_i = w_k + (size_t)i * H_ * HD_;
    const float* wv_i = w_v + (size_t)i * H_ * HD_;
    const float* wo_i = w_o + (size_t)i * 2048 * H_;
    const float* wg_i = w_gate + (size_t)i * H_ * FF_;
    const float* wu_i = w_up + (size_t)i * H_ * FF_;
    const float* wd_i = w_down + (size_t)i * FF_ * H_;
    const float* g_in_gate    = gates + ((size_t)(1 * L_ + i) * 8) * H_;
    const float* g_post_scale = gates + ((size_t)(2 * L_ + i) * 8) * H_;
    const float* g_post_gate  = gates + ((size_t)(3 * L_ + i) * 8) * H_;
    unsigned short* Kf_l = Kf_all + (size_t)i * B_ * TPAD_ * HD_;
    unsigned short* Vt_l = Vt_all + (size_t)i * B_ * HD_ * TPAD_;

    gemmS_k<0, 2><<<dim3(80, 2), 512, 0, stream>>>(normed, H_, H_, wq_i, wk_i, wv_i, qkvpart, nullptr);
    qkvRR_k<<<dim3(QROWS_, B_), 256, 0, stream>>>(qkvpart, offs, q_r, Kf_l, Vt_l);
    scores_k<<<dim3(16, NH_, B_), 256, 0, stream>>>(q_r, Kf_l, scoresb);
    softmax_k<<<dim3(HOR_, NH_, B_), 256, 0, stream>>>(scoresb, Pbuf);
    pvS_k<<<dim3(NH_, B_, 4), 256, 0, stream>>>(Pbuf, Vt_l, attp);
    attR_k<<<1024, 256, 0, stream>>>(attp, attb);
    gemmS_k<1, 4><<<dim3(32, 4), 512, 0, stream>>>(attb, 2048, 2048, wo_i, nullptr, nullptr, wopart, nullptr);
    redA_k<4><<<MPAD_, 256, 0, stream>>>(wopart, hbuf, g_in_gate, post_norm_w + (size_t)i * H_,
                                         g_post_scale, h1buf, normed2);
    gemmS_k<2, 1><<<dim3(128, 1), 512, 0, stream>>>(normed2, H_, H_, wg_i, wu_i, nullptr, nullptr, t_buf);
    gemmS_k<3, 8><<<dim3(32, 8), 512, 0, stream>>>(t_buf, FF_, FF_, wd_i, nullptr, nullptr, dpart, nullptr);
    const float* nw_next = (i + 1 < L_) ? in_norm_w + (size_t)(i + 1) * H_ : fnorm_w;
    const float* sc_next = (i + 1 < L_) ? gates + ((size_t)(0 * L_ + i + 1) * 8) * H_ : fscale;
    redA_k<8><<<MPAD_, 256, 0, stream>>>(dpart, h1buf, g_post_gate, nw_next, sc_next, hbuf, normed);
  }

  fout_k<<<MROWS_, 256, 0, stream>>>(normed, action_out_w, action_out_b, (float*)d_out);
}

// Round 4
// 4153.921 us; speedup vs baseline: 3.2565x; 1.2738x over previous
//
#include <hip/hip_runtime.h>

#define L_ 18
#define H_ 1024
#define NH_ 8
#define HD_ 256
#define FF_ 4096
#define HOR_ 50
#define PRE_ 968
#define B_ 8
#define AD_ 32
#define TPAD_ 1024   // padded KV length (968 prefix + 50 suffix + 6 pad)
#define MROWS_ 400   // B*HOR
#define MPAD_ 512
#define QROWS_ 64    // padded query rows per (b,h)

typedef float f32x4 __attribute__((ext_vector_type(4)));
typedef short s16x4 __attribute__((ext_vector_type(4)));
typedef short s16x8 __attribute__((ext_vector_type(8)));
typedef unsigned short u16x8 __attribute__((ext_vector_type(8)));

__device__ __forceinline__ unsigned short f2bf(float f) {
  unsigned u = __float_as_uint(f);
  u += 0x7FFFu + ((u >> 16) & 1u);   // RTNE (inputs finite)
  return (unsigned short)(u >> 16);
}
__device__ __forceinline__ float bf2f(unsigned short h) {
  return __uint_as_float(((unsigned)h) << 16);
}
__device__ __forceinline__ float wave_max(float v) {
#pragma unroll
  for (int o = 32; o > 0; o >>= 1) v = fmaxf(v, __shfl_xor(v, o));
  return v;
}
__device__ __forceinline__ float wave_sum(float v) {
#pragma unroll
  for (int o = 32; o > 0; o >>= 1) v += __shfl_xor(v, o);
  return v;
}

// ---------------------------------------------------------------- time embedding
__global__ __launch_bounds__(256) void emb_k(const float* __restrict__ ts, float* __restrict__ emb) {
  int b = blockIdx.x, tid = threadIdx.x;
  float t = ts[b];
  for (int j = tid; j < 512; j += 256) {
    float ang = 1570.7963267948966f * expf((float)j * (-6.907755278982137f / 511.0f)) * t;
    emb[(size_t)b * H_ + j] = sinf(ang);
    emb[(size_t)b * H_ + 512 + j] = cosf(ang);
  }
}

// ---------------------------------------------------------------- [8,1024]@[1024,1024] (+bias,+silu)
__global__ __launch_bounds__(256) void gemm8_k(const float* __restrict__ A8, const float* __restrict__ W,
                                               const float* __restrict__ bias, float* __restrict__ out,
                                               int act) {
  __shared__ float a_s[8 * 1024];
  __shared__ float red[4][8][64];
  int tid = threadIdx.x;
  for (int i = tid; i < 8 * 1024; i += 256) a_s[i] = A8[i];
  __syncthreads();
  int nl = tid & 63, kg = tid >> 6;
  int n = blockIdx.x * 64 + nl;
  float acc[8];
#pragma unroll
  for (int m = 0; m < 8; m++) acc[m] = 0.f;
  for (int k = kg * 256; k < kg * 256 + 256; k++) {
    float wv = W[(size_t)k * 1024 + n];
#pragma unroll
    for (int m = 0; m < 8; m++) acc[m] += a_s[m * 1024 + k] * wv;
  }
#pragma unroll
  for (int m = 0; m < 8; m++) red[kg][m][nl] = acc[m];
  __syncthreads();
  if (kg == 0) {
#pragma unroll
    for (int m = 0; m < 8; m++) {
      float v = red[0][m][nl] + red[1][m][nl] + red[2][m][nl] + red[3][m][nl];
      if (bias) v += bias[n];
      if (act) v = v / (1.f + expf(-v));
      out[(size_t)m * 1024 + n] = v;
    }
  }
}

// ---------------------------------------------------------------- all 72 adaLN cond GEMMs in one grid
__global__ __launch_bounds__(256) void gates_k(const float* __restrict__ cond,
                                               const float* __restrict__ w0, const float* __restrict__ w1,
                                               const float* __restrict__ w2, const float* __restrict__ w3,
                                               float* __restrict__ gates) {
  __shared__ float a_s[8 * 1024];
  __shared__ float red[4][8][64];
  int tid = threadIdx.x;
  for (int i = tid; i < 8 * 1024; i += 256) a_s[i] = cond[i];
  __syncthreads();
  int z = blockIdx.z, layer = blockIdx.y;
  const float* W = (z == 0 ? w0 : z == 1 ? w1 : z == 2 ? w2 : w3) + (size_t)layer * H_ * H_;
  float* out = gates + ((size_t)(z * L_ + layer) * 8) * H_;
  int nl = tid & 63, kg = tid >> 6;
  int n = blockIdx.x * 64 + nl;
  float acc[8];
#pragma unroll
  for (int m = 0; m < 8; m++) acc[m] = 0.f;
  for (int k = kg * 256; k < kg * 256 + 256; k++) {
    float wv = W[(size_t)k * 1024 + n];
#pragma unroll
    for (int m = 0; m < 8; m++) acc[m] += a_s[m * 1024 + k] * wv;
  }
#pragma unroll
  for (int m = 0; m < 8; m++) red[kg][m][nl] = acc[m];
  __syncthreads();
  if (kg == 0) {
#pragma unroll
    for (int m = 0; m < 8; m++)
      out[(size_t)m * 1024 + n] = red[0][m][nl] + red[1][m][nl] + red[2][m][nl] + red[3][m][nl];
  }
}

// ---------------------------------------------------------------- pad-mask -> per-batch valid counts
__global__ void offs_k(const unsigned char* __restrict__ mask, int* __restrict__ offs) {
  __shared__ int cnt[8];
  __shared__ int mod4;
  int tid = threadIdx.x;
  if (tid < 8) cnt[tid] = 0;
  if (tid == 8) mod4 = 0;
  __syncthreads();
  for (int i = tid; i < B_ * PRE_; i += 256) {
    unsigned char v = mask[i];
    if (v) {
      atomicAdd(&cnt[i / PRE_], 1);
      if (i & 3) atomicAdd(&mod4, 1);
    }
  }
  __syncthreads();
  if (tid < 8) offs[tid] = (mod4 == 0) ? cnt[tid] * 4 : cnt[tid];
}

// ---------------------------------------------------------------- h = x_t @ action_in_w + b  (pad rows = 0)
__global__ __launch_bounds__(256) void action_in_k(const float* __restrict__ xt, const float* __restrict__ Wi,
                                                   const float* __restrict__ bi, float* __restrict__ h) {
  int idx = blockIdx.x * 256 + threadIdx.x;
  int m = idx >> 10, n = idx & 1023;
  float v = 0.f;
  if (m < MROWS_) {
    const float* xr = xt + (size_t)m * AD_;
#pragma unroll
    for (int k = 0; k < AD_; k++) v += xr[k] * Wi[(size_t)k * H_ + n];
    v += bi[n];
  }
  h[idx] = v;
}

// ---------------------------------------------------------------- AdaRMSNorm -> bf16 (pad rows = 0), layer-0 only
__global__ __launch_bounds__(256) void ada_k(const float* __restrict__ X, const float* __restrict__ nw,
                                             const float* __restrict__ sc, unsigned short* __restrict__ Y) {
  int m = blockIdx.x, tid = threadIdx.x;
  size_t base = (size_t)m * H_;
  if (m >= MROWS_) {
#pragma unroll
    for (int j = 0; j < 4; j++) Y[base + tid * 4 + j] = 0;
    return;
  }
  f32x4 x = *(const f32x4*)(X + base + tid * 4);
  float ss = x[0] * x[0] + x[1] * x[1] + x[2] * x[2] + x[3] * x[3];
  __shared__ float r4[4];
  float wsv = wave_sum(ss);
  if ((tid & 63) == 0) r4[tid >> 6] = wsv;
  __syncthreads();
  float rs = rsqrtf((r4[0] + r4[1] + r4[2] + r4[3]) * (1.f / 1024.f) + 1e-6f);
  int b = m / HOR_;
#pragma unroll
  for (int j = 0; j < 4; j++) {
    int n = tid * 4 + j;
    Y[base + n] = f2bf(x[j] * rs * (1.f + nw[n]) * (1.f + sc[(size_t)b * H_ + n]));
  }
}

// ================================================================ split-K MFMA GEMM stage 1 (16x16x32 MFMA)
// A bf16 [512][lda]; W f32 [Ksz][ldw]; strip = 32 cols (MODE2: 32 gate + 32 up).
// MODE 0=QKV(Ntot 2560; W in {wq,wk,wv}), 1=WO(Ntot 1024), 2=UPGATE(dual; direct t=gelu(g)*u bf16 out),
//      3=DOWN(Ntot 1024). NS = K-split count; grid (nstrips, NS). 512 thr, wave = 64 rows x strip.
#define KSTEP_ 128
#define LST_ 132   // LDS k-stride in shorts

template <int MODE, int NS>
__global__ __launch_bounds__(512) void gemmS_k(const unsigned short* __restrict__ A, int lda, int Ksz,
                                               const float* __restrict__ W0, const float* __restrict__ W1,
                                               const float* __restrict__ W2,
                                               float* __restrict__ part, unsigned short* __restrict__ outT) {
  constexpr int NCOL = (MODE == 2) ? 64 : 32;
  constexpr int NF = NCOL / 16;
  const int tid = threadIdx.x;
  const int wv = tid >> 6, l = tid & 63;
  const int lr = l & 15, lk = (l >> 4) << 2;   // lk*2 = 8*(l>>4) = x32 k-group offset
  const int n0 = blockIdx.x * 32;
  const int kz = blockIdx.y;
  const int KC = Ksz / NS;
  const int kbase = kz * KC;
  const int m0 = wv * 64;

  const float* Wg;
  const float* Wu = nullptr;
  int ldw, wcol, Ntot;
  if (MODE == 0) {
    Ntot = 2560;
    if (n0 < 2048)      { Wg = W0; ldw = 2048; wcol = n0; }
    else if (n0 < 2304) { Wg = W1; ldw = 256;  wcol = n0 - 2048; }
    else                { Wg = W2; ldw = 256;  wcol = n0 - 2304; }
  } else if (MODE == 1) {
    Ntot = 1024; Wg = W0; ldw = 1024; wcol = n0;
  } else if (MODE == 2) {
    Ntot = 4096; Wg = W0; Wu = W1; ldw = 4096; wcol = n0;
  } else {
    Ntot = 1024; Wg = W0; ldw = 1024; wcol = n0;
  }

  __shared__ unsigned short Wt[2][NCOL][LST_];
  const int pr = tid >> 3;          // 0..63: k-pair index within KSTEP
  const int c0 = (tid & 7) * 4;     // col group within strip

  f32x4 acc[4][NF];
#pragma unroll
  for (int a = 0; a < 4; a++)
#pragma unroll
    for (int b = 0; b < NF; b++) acc[a][b] = (f32x4){0.f, 0.f, 0.f, 0.f};

  const int niter = KC / KSTEP_;
  f32x4 pa0, pa1, pb0, pb1;

#define LOADW(IT)                                                                     \
  {                                                                                   \
    size_t kk_ = (size_t)(kbase + (IT) * KSTEP_ + 2 * pr);                            \
    pa0 = *(const f32x4*)(Wg + kk_ * ldw + wcol + c0);                                \
    pa1 = *(const f32x4*)(Wg + (kk_ + 1) * ldw + wcol + c0);                          \
    if (MODE == 2) {                                                                  \
      pb0 = *(const f32x4*)(Wu + kk_ * ldw + wcol + c0);                              \
      pb1 = *(const f32x4*)(Wu + (kk_ + 1) * ldw + wcol + c0);                        \
    }                                                                                 \
  }
#define STOREW(BUF)                                                                   \
  {                                                                                   \
    _Pragma("unroll") for (int j_ = 0; j_ < 4; j_++) {                                \
      unsigned v_ = (unsigned)f2bf(pa0[j_]) | ((unsigned)f2bf(pa1[j_]) << 16);        \
      *(unsigned*)&Wt[BUF][c0 + j_][2 * pr] = v_;                                     \
      if (MODE == 2) {                                                                \
        unsigned u_ = (unsigned)f2bf(pb0[j_]) | ((unsigned)f2bf(pb1[j_]) << 16);      \
        *(unsigned*)&Wt[BUF][32 + c0 + j_][2 * pr] = u_;                              \
      }                                                                               \
    }                                                                                 \
  }

  LOADW(0);
  STOREW(0);
  __syncthreads();

  for (int it = 0; it < niter; ++it) {
    if (it + 1 < niter) LOADW(it + 1);
    const int cur = it & 1;
    const int kb = kbase + it * KSTEP_;
#pragma unroll
    for (int s = 0; s < 4; s++) {   // K=32 per step
      s16x8 bfr[NF];
#pragma unroll
      for (int nf = 0; nf < NF; nf++) {
        s16x4 b0 = *(const s16x4*)&Wt[cur][nf * 16 + lr][s * 32 + 2 * lk];
        s16x4 b1 = *(const s16x4*)&Wt[cur][nf * 16 + lr][s * 32 + 2 * lk + 4];
#pragma unroll
        for (int j = 0; j < 4; j++) { bfr[nf][j] = b0[j]; bfr[nf][4 + j] = b1[j]; }
      }
#pragma unroll
      for (int mf = 0; mf < 4; mf++) {
        s16x8 a = *(const s16x8*)(A + (size_t)(m0 + mf * 16 + lr) * lda + kb + s * 32 + 2 * lk);
#pragma unroll
        for (int nf = 0; nf < NF; nf++)
          acc[mf][nf] = __builtin_amdgcn_mfma_f32_16x16x32_bf16(a, bfr[nf], acc[mf][nf], 0, 0, 0);
      }
    }
    if (it + 1 < niter) STOREW((it + 1) & 1);
    __syncthreads();
  }
#undef LOADW
#undef STOREW

  if (MODE == 2) {
#pragma unroll
    for (int mf = 0; mf < 4; mf++)
#pragma unroll
      for (int nf = 0; nf < 2; nf++)
#pragma unroll
        for (int r = 0; r < 4; r++) {
          int row = m0 + mf * 16 + lk + r;
          int col = n0 + nf * 16 + lr;
          float g = acc[mf][nf][r];
          float u = acc[mf][nf + 2][r];
          g = 0.5f * g * (1.f + tanhf(0.7978845608028654f * (g + 0.044715f * g * g * g)));
          outT[(size_t)row * 4096 + col] = f2bf(g * u);
        }
  } else {
#pragma unroll
    for (int mf = 0; mf < 4; mf++)
#pragma unroll
      for (int nf = 0; nf < NF; nf++)
#pragma unroll
        for (int r = 0; r < 4; r++) {
          int row = m0 + mf * 16 + lk + r;
          int col = n0 + nf * 16 + lr;
          part[((size_t)kz * MPAD_ + row) * Ntot + col] = acc[mf][nf][r];
        }
  }
}

// ---------------------------------------------------------------- split-K reduce + residual-gate + AdaRMSNorm
template <int NS>
__global__ __launch_bounds__(256) void redA_k(const float* __restrict__ part, const float* __restrict__ prev,
                                              const float* __restrict__ gatev, const float* __restrict__ nw,
                                              const float* __restrict__ sc, float* __restrict__ outH,
                                              unsigned short* __restrict__ outN) {
  int r = blockIdx.x, tid = threadIdx.x;
  int c = tid * 4;
  f32x4 h = (f32x4){0.f, 0.f, 0.f, 0.f};
  int b = 0;
  if (r < MROWS_) {
    b = r / HOR_;
    f32x4 v = (f32x4){0.f, 0.f, 0.f, 0.f};
#pragma unroll
    for (int z = 0; z < NS; z++) v += *(const f32x4*)(part + ((size_t)z * MPAD_ + r) * H_ + c);
    f32x4 pv = *(const f32x4*)(prev + (size_t)r * H_ + c);
    f32x4 gv = *(const f32x4*)(gatev + (size_t)b * H_ + c);
    h = pv + gv * v;
  }
  *(f32x4*)(outH + (size_t)r * H_ + c) = h;
  float ss = h[0] * h[0] + h[1] * h[1] + h[2] * h[2] + h[3] * h[3];
  __shared__ float r4[4];
  float wsv = wave_sum(ss);
  if ((tid & 63) == 0) r4[tid >> 6] = wsv;
  __syncthreads();
  float rs = rsqrtf((r4[0] + r4[1] + r4[2] + r4[3]) * (1.f / 1024.f) + 1e-6f);
#pragma unroll
  for (int j = 0; j < 4; j++) {
    int n = c + j;
    outN[(size_t)r * H_ + n] = f2bf(h[j] * rs * (1.f + nw[n]) * (1.f + sc[(size_t)b * H_ + n]));
  }
}

// ---------------------------------------------------------------- QKV reduce(4) + RoPE + scatter
__global__ __launch_bounds__(256) void qkvRR_k(const float* __restrict__ part, const int* __restrict__ offs,
                                               unsigned short* __restrict__ qr, unsigned short* __restrict__ Kf,
                                               unsigned short* __restrict__ Vt) {
  int s = blockIdx.x, b = blockIdx.y, tid = threadIdx.x;
  if (s >= HOR_) {   // zero q_r pad rows
#pragma unroll
    for (int h = 0; h < NH_; h++) qr[(((size_t)(b * NH_ + h)) * QROWS_ + s) * HD_ + tid] = 0;
    return;
  }
  __shared__ float row[2560];
  int m = b * HOR_ + s;
#pragma unroll
  for (int i = 0; i < 10; i++) {
    int c = tid + i * 256;
    float v = 0.f;
#pragma unroll
    for (int z = 0; z < 4; z++) v += part[((size_t)z * MPAD_ + m) * 2560 + c];
    row[c] = v;
  }
  __syncthreads();
  float pos = (float)(offs[b] + s);
#pragma unroll
  for (int it = 0; it < 4; it++) {
    int p = tid + it * 256;
    int h = p >> 7, dd = p & 127;
    float inv = expf((float)dd * (-9.210340371976184f / 128.0f));
    float a = pos * inv;
    float cc = cosf(a), sn = sinf(a);
    float x1 = row[h * HD_ + dd], x2 = row[h * HD_ + dd + 128];
    unsigned short* qo = qr + (((size_t)(b * NH_ + h)) * QROWS_ + s) * HD_;
    qo[dd] = f2bf(x1 * cc - x2 * sn);
    qo[dd + 128] = f2bf(x2 * cc + x1 * sn);
  }
  if (tid < 128) {
    int dd = tid;
    float inv = expf((float)dd * (-9.210340371976184f / 128.0f));
    float a = pos * inv;
    float cc = cosf(a), sn = sinf(a);
    float x1 = row[2048 + dd], x2 = row[2048 + dd + 128];
    unsigned short* ko = Kf + ((size_t)b * TPAD_ + PRE_ + s) * HD_;
    ko[dd] = f2bf(x1 * cc - x2 * sn);
    ko[dd + 128] = f2bf(x2 * cc + x1 * sn);
  }
  Vt[((size_t)(b * HD_ + tid)) * TPAD_ + PRE_ + s] = f2bf(row[2304 + tid]);
}

// ---------------------------------------------------------------- all-layer prefix convert: K row-major, V transposed
__global__ __launch_bounds__(256) void prefixAll_k(const float* __restrict__ pk, const float* __restrict__ pv,
                                                   unsigned short* __restrict__ Kf_all,
                                                   unsigned short* __restrict__ Vt_all) {
  int b = blockIdx.y, t0 = blockIdx.x * 64, layer = blockIdx.z, tid = threadIdx.x;
  unsigned short* Kf = Kf_all + (size_t)layer * B_ * TPAD_ * HD_;
  unsigned short* Vt = Vt_all + (size_t)layer * B_ * HD_ * TPAD_;
  __shared__ unsigned short vt[256][72];
  const float* kp = pk + ((size_t)(b * L_ + layer)) * PRE_ * HD_;
  const float* vp = pv + ((size_t)(b * L_ + layer)) * PRE_ * HD_;
  for (int i = 0; i < 64; i++) {
    int t = t0 + i;
    float kv = 0.f, vv = 0.f;
    if (t < PRE_) {
      kv = kp[(size_t)t * HD_ + tid];
      vv = vp[(size_t)t * HD_ + tid];
    }
    Kf[((size_t)b * TPAD_ + t) * HD_ + tid] = f2bf(kv);  // suffix rows overwritten by qkvRR later
    vt[tid][i] = f2bf(vv);
  }
  __syncthreads();
#pragma unroll
  for (int p = 0; p < 4; p++) {
    int d = p * 64 + (tid >> 2);
    int c0 = (tid & 3) * 16;
    u16x8 v0, v1;
#pragma unroll
    for (int j = 0; j < 8; j++) { v0[j] = vt[d][c0 + j]; v1[j] = vt[d][c0 + 8 + j]; }
    size_t dst = ((size_t)(b * HD_ + d)) * TPAD_ + t0 + c0;
    *(u16x8*)(Vt + dst) = v0;
    *(u16x8*)(Vt + dst + 8) = v1;
  }
}

// ---------------------------------------------------------------- split-KV flash attention (one KV chunk of 256)
// grid (4, NH, B), 256 thr. Wave w handles q-rows w*16..w*16+15. Outputs unnormalized O + (m,l).
__global__ __launch_bounds__(256) void flash_k(const unsigned short* __restrict__ qr,
                                               const unsigned short* __restrict__ Kf,
                                               const unsigned short* __restrict__ Vt,
                                               float* __restrict__ Op, float* __restrict__ stats) {
  const int z = blockIdx.x, h = blockIdx.y, b = blockIdx.z;
  const int bh = b * NH_ + h;
  const int tid = threadIdx.x, w = tid >> 6, l = tid & 63;
  const int lr = l & 15, kg = l >> 4;
  const int t0 = z * 256;
  __shared__ unsigned short P_lds[64][264];

  // ---- QK^T (16 rows x 256 t per wave)
  f32x4 sc[16];
#pragma unroll
  for (int nf = 0; nf < 16; nf++) sc[nf] = (f32x4){0.f, 0.f, 0.f, 0.f};
  const unsigned short* qbase = qr + ((size_t)bh * QROWS_ + w * 16 + lr) * HD_;
  const unsigned short* kbase = Kf + ((size_t)b * TPAD_ + t0 + lr) * HD_;
#pragma unroll
  for (int k0 = 0; k0 < HD_; k0 += 32) {
    s16x8 a = *(const s16x8*)(qbase + k0 + 8 * kg);
#pragma unroll
    for (int nf = 0; nf < 16; nf++) {
      s16x8 bv = *(const s16x8*)(kbase + (size_t)nf * 16 * HD_ + k0 + 8 * kg);
      sc[nf] = __builtin_amdgcn_mfma_f32_16x16x32_bf16(a, bv, sc[nf], 0, 0, 0);
    }
  }
  // ---- scale + mask + row softmax (full chunk in regs)
  float mx[4] = {-3.0e38f, -3.0e38f, -3.0e38f, -3.0e38f};
#pragma unroll
  for (int nf = 0; nf < 16; nf++) {
    int t = t0 + nf * 16 + lr;
#pragma unroll
    for (int r = 0; r < 4; r++) {
      int row = w * 16 + 4 * kg + r;
      float v = sc[nf][r] * 0.0625f;
      if (t >= PRE_ && (t - PRE_) > row) v = -1e9f;
      sc[nf][r] = v;
      mx[r] = fmaxf(mx[r], v);
    }
  }
#pragma unroll
  for (int o = 8; o > 0; o >>= 1)
#pragma unroll
    for (int r = 0; r < 4; r++) mx[r] = fmaxf(mx[r], __shfl_xor(mx[r], o));
  float ls[4] = {0.f, 0.f, 0.f, 0.f};
#pragma unroll
  for (int nf = 0; nf < 16; nf++)
#pragma unroll
    for (int r = 0; r < 4; r++) {
      float p = expf(sc[nf][r] - mx[r]);
      sc[nf][r] = p;
      ls[r] += p;
    }
#pragma unroll
  for (int o = 8; o > 0; o >>= 1)
#pragma unroll
    for (int r = 0; r < 4; r++) ls[r] += __shfl_xor(ls[r], o);
  // ---- P -> LDS (bf16), stats out
#pragma unroll
  for (int nf = 0; nf < 16; nf++)
#pragma unroll
    for (int r = 0; r < 4; r++) P_lds[w * 16 + 4 * kg + r][nf * 16 + lr] = f2bf(sc[nf][r]);
  if (lr == 0) {
#pragma unroll
    for (int r = 0; r < 4; r++) {
      int row = w * 16 + 4 * kg + r;
      size_t si = (((size_t)z * 64 + bh) * 64 + row) * 2;
      stats[si] = mx[r];
      stats[si + 1] = ls[r];
    }
  }
  __syncthreads();
  // ---- PV (unnormalized): O[16 rows][256 d]
  f32x4 o4[16];
#pragma unroll
  for (int nf = 0; nf < 16; nf++) o4[nf] = (f32x4){0.f, 0.f, 0.f, 0.f};
  const unsigned short* vbase = Vt + ((size_t)(b * HD_ + lr)) * TPAD_ + t0;
#pragma unroll
  for (int ti = 0; ti < 256; ti += 32) {
    s16x8 a = *(const s16x8*)&P_lds[w * 16 + lr][ti + 8 * kg];
#pragma unroll
    for (int nf = 0; nf < 16; nf++) {
      s16x8 bv = *(const s16x8*)(vbase + (size_t)nf * 16 * TPAD_ + ti + 8 * kg);
      o4[nf] = __builtin_amdgcn_mfma_f32_16x16x32_bf16(a, bv, o4[nf], 0, 0, 0);
    }
  }
#pragma unroll
  for (int nf = 0; nf < 16; nf++)
#pragma unroll
    for (int r = 0; r < 4; r++) {
      int row = w * 16 + 4 * kg + r;
      Op[(((size_t)z * 64 + bh) * 64 + row) * HD_ + nf * 16 + lr] = o4[nf][r];
    }
}

// ---------------------------------------------------------------- flash combine: 4 chunks -> attb (valid rows only)
__global__ __launch_bounds__(256) void comb_k(const float* __restrict__ Op, const float* __restrict__ stats,
                                              unsigned short* __restrict__ attb) {
  int s = blockIdx.x, h = blockIdx.y, b = blockIdx.z;
  int bh = b * NH_ + h, d = threadIdx.x;
  float mz[4], lz[4];
  float M = -3.0e38f;
#pragma unroll
  for (int z = 0; z < 4; z++) {
    size_t si = (((size_t)z * 64 + bh) * 64 + s) * 2;
    mz[z] = stats[si];
    lz[z] = stats[si + 1];
    M = fmaxf(M, mz[z]);
  }
  float lsum = 0.f, o = 0.f;
#pragma unroll
  for (int z = 0; z < 4; z++) {
    float wz = expf(mz[z] - M);
    lsum += wz * lz[z];
    o += wz * Op[(((size_t)z * 64 + bh) * 64 + s) * HD_ + d];
  }
  attb[((size_t)(b * HOR_ + s)) * 2048 + h * HD_ + d] = f2bf(o / lsum);
}

// ---------------------------------------------------------------- out = normedF @ action_out_w + b
__global__ __launch_bounds__(256) void fout_k(const unsigned short* __restrict__ nf, const float* __restrict__ Wo,
                                              const float* __restrict__ bo, float* __restrict__ out) {
  int m = blockIdx.x, tid = threadIdx.x;
  int n = tid & 31, kg = tid >> 5;
  float acc = 0.f;
  for (int k = kg * 128; k < kg * 128 + 128; k++)
    acc += bf2f(nf[(size_t)m * H_ + k]) * Wo[(size_t)k * AD_ + n];
  __shared__ float red[8][32];
  red[kg][n] = acc;
  __syncthreads();
  if (kg == 0) {
    float v = 0.f;
#pragma unroll
    for (int g = 0; g < 8; g++) v += red[g][n];
    out[(size_t)m * AD_ + n] = v + bo[n];
  }
}

// ================================================================ host
extern "C" void kernel_launch(void* const* d_in, const int* in_sizes, int n_in,
                              void* d_out, int out_size, void* d_ws, size_t ws_size,
                              hipStream_t stream) {
  const float* prefix_keys   = (const float*)d_in[0];
  const float* prefix_values = (const float*)d_in[1];
  const float* x_t           = (const float*)d_in[2];
  const float* timestep      = (const float*)d_in[3];
  const unsigned char* pad_mask = (const unsigned char*)d_in[4];
  const float* action_in_w   = (const float*)d_in[5];
  const float* action_in_b   = (const float*)d_in[6];
  const float* action_out_w  = (const float*)d_in[7];
  const float* action_out_b  = (const float*)d_in[8];
  const float* tmlp_in_w     = (const float*)d_in[9];
  const float* tmlp_in_b     = (const float*)d_in[10];
  const float* tmlp_out_w    = (const float*)d_in[11];
  const float* tmlp_out_b    = (const float*)d_in[12];
  const float* w_q    = (const float*)d_in[13];
  const float* w_k    = (const float*)d_in[14];
  const float* w_v    = (const float*)d_in[15];
  const float* w_o    = (const float*)d_in[16];
  const float* w_gate = (const float*)d_in[17];
  const float* w_up   = (const float*)d_in[18];
  const float* w_down = (const float*)d_in[19];
  const float* in_norm_w    = (const float*)d_in[20];
  const float* in_scale_w   = (const float*)d_in[21];
  const float* in_gate_w    = (const float*)d_in[22];
  const float* post_norm_w  = (const float*)d_in[23];
  const float* post_scale_w = (const float*)d_in[24];
  const float* post_gate_w  = (const float*)d_in[25];
  const float* fnorm_w       = (const float*)d_in[26];
  const float* fnorm_scale_w = (const float*)d_in[27];

  char* wsp = (char*)d_ws;
  auto alloc = [&](size_t bytes) { void* p = (void*)wsp; wsp += (bytes + 255) & ~(size_t)255; return p; };

  float* emb0   = (float*)alloc((size_t)8 * H_ * 4);
  float* emb1   = (float*)alloc((size_t)8 * H_ * 4);
  float* cond   = (float*)alloc((size_t)8 * H_ * 4);
  float* fscale = (float*)alloc((size_t)8 * H_ * 4);
  float* gates  = (float*)alloc((size_t)4 * L_ * 8 * H_ * 4);
  int*   offs   = (int*)alloc(64);
  float* hbuf   = (float*)alloc((size_t)MPAD_ * H_ * 4);
  float* h1buf  = (float*)alloc((size_t)MPAD_ * H_ * 4);
  unsigned short* normed  = (unsigned short*)alloc((size_t)MPAD_ * H_ * 2);
  unsigned short* normed2 = (unsigned short*)alloc((size_t)MPAD_ * H_ * 2);
  unsigned short* q_r     = (unsigned short*)alloc((size_t)B_ * NH_ * QROWS_ * HD_ * 2);
  unsigned short* Kf_all  = (unsigned short*)alloc((size_t)L_ * B_ * TPAD_ * HD_ * 2);
  unsigned short* Vt_all  = (unsigned short*)alloc((size_t)L_ * B_ * HD_ * TPAD_ * 2);
  unsigned short* attb    = (unsigned short*)alloc((size_t)MPAD_ * 2048 * 2);
  unsigned short* t_buf   = (unsigned short*)alloc((size_t)MPAD_ * FF_ * 2);
  float* qkvpart = (float*)alloc((size_t)4 * MPAD_ * 2560 * 4);
  float* wopart  = (float*)alloc((size_t)8 * MPAD_ * 1024 * 4);
  float* dpart   = (float*)alloc((size_t)8 * MPAD_ * 1024 * 4);
  float* Opart   = (float*)alloc((size_t)4 * 64 * QROWS_ * HD_ * 4);
  float* statsb  = (float*)alloc((size_t)4 * 64 * QROWS_ * 2 * 4);

  // attb pad rows (400..511) are never written by comb_k: zero once (stays zero all layers)
  hipMemsetAsync(attb + (size_t)MROWS_ * 2048, 0, (size_t)(MPAD_ - MROWS_) * 2048 * 2, stream);

  emb_k<<<8, 256, 0, stream>>>(timestep, emb0);
  gemm8_k<<<16, 256, 0, stream>>>(emb0, tmlp_in_w, tmlp_in_b, emb1, 1);
  gemm8_k<<<16, 256, 0, stream>>>(emb1, tmlp_out_w, tmlp_out_b, cond, 1);
  gemm8_k<<<16, 256, 0, stream>>>(cond, fnorm_scale_w, nullptr, fscale, 0);
  gates_k<<<dim3(16, L_, 4), 256, 0, stream>>>(cond, in_scale_w, in_gate_w, post_scale_w, post_gate_w, gates);
  offs_k<<<1, 256, 0, stream>>>(pad_mask, offs);
  action_in_k<<<(MPAD_ * H_) / 256, 256, 0, stream>>>(x_t, action_in_w, action_in_b, hbuf);
  prefixAll_k<<<dim3(16, B_, L_), 256, 0, stream>>>(prefix_keys, prefix_values, Kf_all, Vt_all);
  ada_k<<<MPAD_, 256, 0, stream>>>(hbuf, in_norm_w, gates + 0, normed);  // layer 0 in_scale = gates[0][0]

  for (int i = 0; i < L_; i++) {
    const float* wq_i = w_q + (size_t)i * H_ * 2048;
    const float* wk_i = w_k + (size_t)i * H_ * HD_;
    const float* wv_i = w_v + (size_t)i * H_ * HD_;
    const float* wo_i = w_o + (size_t)i * 2048 * H_;
    const float* wg_i = w_gate + (size_t)i * H_ * FF_;
    const float* wu_i = w_up + (size_t)i * H_ * FF_;
    const float* wd_i = w_down + (size_t)i * FF_ * H_;
    const float* g_in_gate    = gates + ((size_t)(1 * L_ + i) * 8) * H_;
    const float* g_post_scale = gates + ((size_t)(2 * L_ + i) * 8) * H_;
    const float* g_post_gate  = gates + ((size_t)(3 * L_ + i) * 8) * H_;
    unsigned short* Kf_l = Kf_all + (size_t)i * B_ * TPAD_ * HD_;
    unsigned short* Vt_l = Vt_all + (size_t)i * B_ * HD_ * TPAD_;

    gemmS_k<0, 4><<<dim3(80, 4), 512, 0, stream>>>(normed, H_, H_, wq_i, wk_i, wv_i, qkvpart, nullptr);
    qkvRR_k<<<dim3(QROWS_, B_), 256, 0, stream>>>(qkvpart, offs, q_r, Kf_l, Vt_l);
    flash_k<<<dim3(4, NH_, B_), 256, 0, stream>>>(q_r, Kf_l, Vt_l, Opart, statsb);
    comb_k<<<dim3(HOR_, NH_, B_), 256, 0, stream>>>(Opart, statsb, attb);
    gemmS_k<1, 8><<<dim3(32, 8), 512, 0, stream>>>(attb, 2048, 2048, wo_i, nullptr, nullptr, wopart, nullptr);
    redA_k<8><<<MPAD_, 256, 0, stream>>>(wopart, hbuf, g_in_gate, post_norm_w + (size_t)i * H_,
                                         g_post_scale, h1buf, normed2);
    gemmS_k<2, 1><<<dim3(128, 1), 512, 0, stream>>>(normed2, H_, H_, wg_i, wu_i, nullptr, nullptr, t_buf);
    gemmS_k<3, 8><<<dim3(32, 8), 512, 0, stream>>>(t_buf, FF_, FF_, wd_i, nullptr, nullptr, dpart, nullptr);
    const float* nw_next = (i + 1 < L_) ? in_norm_w + (size_t)(i + 1) * H_ : fnorm_w;
    const float* sc_next = (i + 1 < L_) ? gates + ((size_t)(0 * L_ + i + 1) * 8) * H_ : fscale;
    redA_k<8><<<MPAD_, 256, 0, stream>>>(dpart, h1buf, g_post_gate, nw_next, sc_next, hbuf, normed);
  }

  fout_k<<<MROWS_, 256, 0, stream>>>(normed, action_out_w, action_out_b, (float*)d_out);
}

// Round 5
// 3759.253 us; speedup vs baseline: 3.5984x; 1.1050x over previous
//
#include <hip/hip_runtime.h>

#define L_ 18
#define H_ 1024
#define NH_ 8
#define HD_ 256
#define FF_ 4096
#define HOR_ 50
#define PRE_ 968
#define B_ 8
#define AD_ 32
#define TPAD_ 1024   // padded KV length (968 prefix + 50 suffix + 6 pad)
#define MROWS_ 400   // B*HOR
#define MPAD_ 512
#define QROWS_ 64    // padded query rows per (b,h)

typedef float f32x4 __attribute__((ext_vector_type(4)));
typedef short s16x4 __attribute__((ext_vector_type(4)));
typedef short s16x8 __attribute__((ext_vector_type(8)));
typedef unsigned short u16x8 __attribute__((ext_vector_type(8)));

__device__ __forceinline__ unsigned short f2bf(float f) {
  unsigned u = __float_as_uint(f);
  u += 0x7FFFu + ((u >> 16) & 1u);   // RTNE (inputs finite)
  return (unsigned short)(u >> 16);
}
__device__ __forceinline__ float bf2f(unsigned short h) {
  return __uint_as_float(((unsigned)h) << 16);
}
__device__ __forceinline__ float wave_sum(float v) {
#pragma unroll
  for (int o = 32; o > 0; o >>= 1) v += __shfl_xor(v, o);
  return v;
}

// ---------------------------------------------------------------- time embedding
__global__ __launch_bounds__(256) void emb_k(const float* __restrict__ ts, float* __restrict__ emb) {
  int b = blockIdx.x, tid = threadIdx.x;
  float t = ts[b];
  for (int j = tid; j < 512; j += 256) {
    float ang = 1570.7963267948966f * expf((float)j * (-6.907755278982137f / 511.0f)) * t;
    emb[(size_t)b * H_ + j] = sinf(ang);
    emb[(size_t)b * H_ + 512 + j] = cosf(ang);
  }
}

// ---------------------------------------------------------------- [8,1024]@[1024,1024] (+bias,+silu)
__global__ __launch_bounds__(256) void gemm8_k(const float* __restrict__ A8, const float* __restrict__ W,
                                               const float* __restrict__ bias, float* __restrict__ out,
                                               int act) {
  __shared__ float a_s[8 * 1024];
  __shared__ float red[4][8][64];
  int tid = threadIdx.x;
  for (int i = tid; i < 8 * 1024; i += 256) a_s[i] = A8[i];
  __syncthreads();
  int nl = tid & 63, kg = tid >> 6;
  int n = blockIdx.x * 64 + nl;
  float acc[8];
#pragma unroll
  for (int m = 0; m < 8; m++) acc[m] = 0.f;
  for (int k = kg * 256; k < kg * 256 + 256; k++) {
    float wv = W[(size_t)k * 1024 + n];
#pragma unroll
    for (int m = 0; m < 8; m++) acc[m] += a_s[m * 1024 + k] * wv;
  }
#pragma unroll
  for (int m = 0; m < 8; m++) red[kg][m][nl] = acc[m];
  __syncthreads();
  if (kg == 0) {
#pragma unroll
    for (int m = 0; m < 8; m++) {
      float v = red[0][m][nl] + red[1][m][nl] + red[2][m][nl] + red[3][m][nl];
      if (bias) v += bias[n];
      if (act) v = v / (1.f + expf(-v));
      out[(size_t)m * 1024 + n] = v;
    }
  }
}

// ---------------------------------------------------------------- all 72 adaLN cond GEMMs in one grid
__global__ __launch_bounds__(256) void gates_k(const float* __restrict__ cond,
                                               const float* __restrict__ w0, const float* __restrict__ w1,
                                               const float* __restrict__ w2, const float* __restrict__ w3,
                                               float* __restrict__ gates) {
  __shared__ float a_s[8 * 1024];
  __shared__ float red[4][8][64];
  int tid = threadIdx.x;
  for (int i = tid; i < 8 * 1024; i += 256) a_s[i] = cond[i];
  __syncthreads();
  int z = blockIdx.z, layer = blockIdx.y;
  const float* W = (z == 0 ? w0 : z == 1 ? w1 : z == 2 ? w2 : w3) + (size_t)layer * H_ * H_;
  float* out = gates + ((size_t)(z * L_ + layer) * 8) * H_;
  int nl = tid & 63, kg = tid >> 6;
  int n = blockIdx.x * 64 + nl;
  float acc[8];
#pragma unroll
  for (int m = 0; m < 8; m++) acc[m] = 0.f;
  for (int k = kg * 256; k < kg * 256 + 256; k++) {
    float wv = W[(size_t)k * 1024 + n];
#pragma unroll
    for (int m = 0; m < 8; m++) acc[m] += a_s[m * 1024 + k] * wv;
  }
#pragma unroll
  for (int m = 0; m < 8; m++) red[kg][m][nl] = acc[m];
  __syncthreads();
  if (kg == 0) {
#pragma unroll
    for (int m = 0; m < 8; m++)
      out[(size_t)m * 1024 + n] = red[0][m][nl] + red[1][m][nl] + red[2][m][nl] + red[3][m][nl];
  }
}

// ---------------------------------------------------------------- pad-mask -> per-batch valid counts
__global__ void offs_k(const unsigned char* __restrict__ mask, int* __restrict__ offs) {
  __shared__ int cnt[8];
  __shared__ int mod4;
  int tid = threadIdx.x;
  if (tid < 8) cnt[tid] = 0;
  if (tid == 8) mod4 = 0;
  __syncthreads();
  for (int i = tid; i < B_ * PRE_; i += 256) {
    unsigned char v = mask[i];
    if (v) {
      atomicAdd(&cnt[i / PRE_], 1);
      if (i & 3) atomicAdd(&mod4, 1);
    }
  }
  __syncthreads();
  if (tid < 8) offs[tid] = (mod4 == 0) ? cnt[tid] * 4 : cnt[tid];
}

// ---------------------------------------------------------------- h = x_t @ action_in_w + b  (pad rows = 0)
__global__ __launch_bounds__(256) void action_in_k(const float* __restrict__ xt, const float* __restrict__ Wi,
                                                   const float* __restrict__ bi, float* __restrict__ h) {
  int idx = blockIdx.x * 256 + threadIdx.x;
  int m = idx >> 10, n = idx & 1023;
  float v = 0.f;
  if (m < MROWS_) {
    const float* xr = xt + (size_t)m * AD_;
#pragma unroll
    for (int k = 0; k < AD_; k++) v += xr[k] * Wi[(size_t)k * H_ + n];
    v += bi[n];
  }
  h[idx] = v;
}

// ---------------------------------------------------------------- AdaRMSNorm -> bf16 (pad rows = 0), layer-0 only
__global__ __launch_bounds__(256) void ada_k(const float* __restrict__ X, const float* __restrict__ nw,
                                             const float* __restrict__ sc, unsigned short* __restrict__ Y) {
  int m = blockIdx.x, tid = threadIdx.x;
  size_t base = (size_t)m * H_;
  if (m >= MROWS_) {
#pragma unroll
    for (int j = 0; j < 4; j++) Y[base + tid * 4 + j] = 0;
    return;
  }
  f32x4 x = *(const f32x4*)(X + base + tid * 4);
  float ss = x[0] * x[0] + x[1] * x[1] + x[2] * x[2] + x[3] * x[3];
  __shared__ float r4[4];
  float wsv = wave_sum(ss);
  if ((tid & 63) == 0) r4[tid >> 6] = wsv;
  __syncthreads();
  float rs = rsqrtf((r4[0] + r4[1] + r4[2] + r4[3]) * (1.f / 1024.f) + 1e-6f);
  int b = m / HOR_;
#pragma unroll
  for (int j = 0; j < 4; j++) {
    int n = tid * 4 + j;
    Y[base + n] = f2bf(x[j] * rs * (1.f + nw[n]) * (1.f + sc[(size_t)b * H_ + n]));
  }
}

// ================================================================ split-K MFMA GEMM stage 1 (16x16x32 MFMA)
// A bf16 [512][lda]; W f32 [Ksz][ldw]; strip = 32 cols (MODE2: 32 gate + 32 up).
// MODE 0=QKV(Ntot 2560), 1=WO, 2=UPGATE(dual strips; direct t=gelu(g)*u bf16), 3=DOWN.
// NS = K-split; MS = M-split. grid (nstrips, NS, MS). 512 thr = 8 waves; wave = (64/MS) rows.
#define KSTEP_ 128
#define LST_ 132   // LDS k-stride in shorts

template <int MODE, int NS, int MS>
__global__ __launch_bounds__(512) void gemmS_k(const unsigned short* __restrict__ A, int lda, int Ksz,
                                               const float* __restrict__ W0, const float* __restrict__ W1,
                                               const float* __restrict__ W2,
                                               float* __restrict__ part, unsigned short* __restrict__ outT) {
  constexpr int NCOL = (MODE == 2) ? 64 : 32;
  constexpr int NF = NCOL / 16;
  constexpr int RPW = 64 / MS;     // rows per wave
  constexpr int MFC = RPW / 16;    // m-fragments per wave
  const int tid = threadIdx.x;
  const int wv = tid >> 6, l = tid & 63;
  const int lr = l & 15, lk = (l >> 4) << 2;   // 2*lk = x32 k-group byte offset base
  const int n0 = blockIdx.x * 32;
  const int kz = blockIdx.y;
  const int KC = Ksz / NS;
  const int kbase = kz * KC;
  const int m0 = (int)blockIdx.z * (512 / MS) + wv * RPW;

  const float* Wg;
  const float* Wu = nullptr;
  int ldw, wcol, Ntot;
  if (MODE == 0) {
    Ntot = 2560;
    if (n0 < 2048)      { Wg = W0; ldw = 2048; wcol = n0; }
    else if (n0 < 2304) { Wg = W1; ldw = 256;  wcol = n0 - 2048; }
    else                { Wg = W2; ldw = 256;  wcol = n0 - 2304; }
  } else if (MODE == 1) {
    Ntot = 1024; Wg = W0; ldw = 1024; wcol = n0;
  } else if (MODE == 2) {
    Ntot = 4096; Wg = W0; Wu = W1; ldw = 4096; wcol = n0;
  } else {
    Ntot = 1024; Wg = W0; ldw = 1024; wcol = n0;
  }

  __shared__ unsigned short Wt[2][NCOL][LST_];
  const int pr = tid >> 3;          // 0..63: k-pair index within KSTEP
  const int c0 = (tid & 7) * 4;     // col group within strip

  f32x4 acc[MFC][NF];
#pragma unroll
  for (int a = 0; a < MFC; a++)
#pragma unroll
    for (int b = 0; b < NF; b++) acc[a][b] = (f32x4){0.f, 0.f, 0.f, 0.f};

  const int niter = KC / KSTEP_;
  f32x4 pa0, pa1, pb0, pb1;

#define LOADW(IT)                                                                     \
  {                                                                                   \
    size_t kk_ = (size_t)(kbase + (IT) * KSTEP_ + 2 * pr);                            \
    pa0 = *(const f32x4*)(Wg + kk_ * ldw + wcol + c0);                                \
    pa1 = *(const f32x4*)(Wg + (kk_ + 1) * ldw + wcol + c0);                          \
    if (MODE == 2) {                                                                  \
      pb0 = *(const f32x4*)(Wu + kk_ * ldw + wcol + c0);                              \
      pb1 = *(const f32x4*)(Wu + (kk_ + 1) * ldw + wcol + c0);                        \
    }                                                                                 \
  }
#define STOREW(BUF)                                                                   \
  {                                                                                   \
    _Pragma("unroll") for (int j_ = 0; j_ < 4; j_++) {                                \
      unsigned v_ = (unsigned)f2bf(pa0[j_]) | ((unsigned)f2bf(pa1[j_]) << 16);        \
      *(unsigned*)&Wt[BUF][c0 + j_][2 * pr] = v_;                                     \
      if (MODE == 2) {                                                                \
        unsigned u_ = (unsigned)f2bf(pb0[j_]) | ((unsigned)f2bf(pb1[j_]) << 16);      \
        *(unsigned*)&Wt[BUF][32 + c0 + j_][2 * pr] = u_;                              \
      }                                                                               \
    }                                                                                 \
  }

  LOADW(0);
  STOREW(0);
  __syncthreads();

  for (int it = 0; it < niter; ++it) {
    if (it + 1 < niter) LOADW(it + 1);
    const int cur = it & 1;
    const int kb = kbase + it * KSTEP_;
#pragma unroll
    for (int s = 0; s < 4; s++) {   // K=32 per step
      s16x8 bfr[NF];
#pragma unroll
      for (int nf = 0; nf < NF; nf++) {
        s16x4 b0 = *(const s16x4*)&Wt[cur][nf * 16 + lr][s * 32 + 2 * lk];
        s16x4 b1 = *(const s16x4*)&Wt[cur][nf * 16 + lr][s * 32 + 2 * lk + 4];
#pragma unroll
        for (int j = 0; j < 4; j++) { bfr[nf][j] = b0[j]; bfr[nf][4 + j] = b1[j]; }
      }
#pragma unroll
      for (int mf = 0; mf < MFC; mf++) {
        s16x8 a = *(const s16x8*)(A + (size_t)(m0 + mf * 16 + lr) * lda + kb + s * 32 + 2 * lk);
#pragma unroll
        for (int nf = 0; nf < NF; nf++)
          acc[mf][nf] = __builtin_amdgcn_mfma_f32_16x16x32_bf16(a, bfr[nf], acc[mf][nf], 0, 0, 0);
      }
    }
    if (it + 1 < niter) STOREW((it + 1) & 1);
    __syncthreads();
  }
#undef LOADW
#undef STOREW

  if (MODE == 2) {
#pragma unroll
    for (int mf = 0; mf < MFC; mf++)
#pragma unroll
      for (int nf = 0; nf < 2; nf++)
#pragma unroll
        for (int r = 0; r < 4; r++) {
          int row = m0 + mf * 16 + lk + r;
          if (row >= MROWS_) continue;
          int col = n0 + nf * 16 + lr;
          float g = acc[mf][nf][r];
          float u = acc[mf][nf + 2][r];
          g = 0.5f * g * (1.f + tanhf(0.7978845608028654f * (g + 0.044715f * g * g * g)));
          outT[(size_t)row * 4096 + col] = f2bf(g * u);
        }
  } else {
#pragma unroll
    for (int mf = 0; mf < MFC; mf++)
#pragma unroll
      for (int nf = 0; nf < NF; nf++)
#pragma unroll
        for (int r = 0; r < 4; r++) {
          int row = m0 + mf * 16 + lk + r;
          if (row >= MROWS_) continue;
          int col = n0 + nf * 16 + lr;
          part[((size_t)kz * MPAD_ + row) * Ntot + col] = acc[mf][nf][r];
        }
  }
}

// ---------------------------------------------------------------- split-K reduce + residual-gate + AdaRMSNorm
template <int NS>
__global__ __launch_bounds__(256) void redA_k(const float* __restrict__ part, const float* __restrict__ prev,
                                              const float* __restrict__ gatev, const float* __restrict__ nw,
                                              const float* __restrict__ sc, float* __restrict__ outH,
                                              unsigned short* __restrict__ outN) {
  int r = blockIdx.x, tid = threadIdx.x;
  int c = tid * 4;
  f32x4 h = (f32x4){0.f, 0.f, 0.f, 0.f};
  int b = 0;
  if (r < MROWS_) {
    b = r / HOR_;
    f32x4 v = (f32x4){0.f, 0.f, 0.f, 0.f};
#pragma unroll
    for (int z = 0; z < NS; z++) v += *(const f32x4*)(part + ((size_t)z * MPAD_ + r) * H_ + c);
    f32x4 pv = *(const f32x4*)(prev + (size_t)r * H_ + c);
    f32x4 gv = *(const f32x4*)(gatev + (size_t)b * H_ + c);
    h = pv + gv * v;
  }
  *(f32x4*)(outH + (size_t)r * H_ + c) = h;
  float ss = h[0] * h[0] + h[1] * h[1] + h[2] * h[2] + h[3] * h[3];
  __shared__ float r4[4];
  float wsv = wave_sum(ss);
  if ((tid & 63) == 0) r4[tid >> 6] = wsv;
  __syncthreads();
  float rs = rsqrtf((r4[0] + r4[1] + r4[2] + r4[3]) * (1.f / 1024.f) + 1e-6f);
#pragma unroll
  for (int j = 0; j < 4; j++) {
    int n = c + j;
    outN[(size_t)r * H_ + n] = f2bf(h[j] * rs * (1.f + nw[n]) * (1.f + sc[(size_t)b * H_ + n]));
  }
}

// ---------------------------------------------------------------- QKV reduce(2) + RoPE + scatter
__global__ __launch_bounds__(256) void qkvRR_k(const float* __restrict__ part, const int* __restrict__ offs,
                                               unsigned short* __restrict__ qr, unsigned short* __restrict__ Kf,
                                               unsigned short* __restrict__ Vt) {
  int s = blockIdx.x, b = blockIdx.y, tid = threadIdx.x;
  if (s >= HOR_) {   // zero q_r pad rows
#pragma unroll
    for (int h = 0; h < NH_; h++) qr[(((size_t)(b * NH_ + h)) * QROWS_ + s) * HD_ + tid] = 0;
    return;
  }
  __shared__ float row[2560];
  int m = b * HOR_ + s;
#pragma unroll
  for (int i = 0; i < 10; i++) {
    int c = tid + i * 256;
    row[c] = part[((size_t)0 * MPAD_ + m) * 2560 + c] + part[((size_t)1 * MPAD_ + m) * 2560 + c];
  }
  __syncthreads();
  float pos = (float)(offs[b] + s);
#pragma unroll
  for (int it = 0; it < 4; it++) {
    int p = tid + it * 256;
    int h = p >> 7, dd = p & 127;
    float inv = expf((float)dd * (-9.210340371976184f / 128.0f));
    float a = pos * inv;
    float cc = cosf(a), sn = sinf(a);
    float x1 = row[h * HD_ + dd], x2 = row[h * HD_ + dd + 128];
    unsigned short* qo = qr + (((size_t)(b * NH_ + h)) * QROWS_ + s) * HD_;
    qo[dd] = f2bf(x1 * cc - x2 * sn);
    qo[dd + 128] = f2bf(x2 * cc + x1 * sn);
  }
  if (tid < 128) {
    int dd = tid;
    float inv = expf((float)dd * (-9.210340371976184f / 128.0f));
    float a = pos * inv;
    float cc = cosf(a), sn = sinf(a);
    float x1 = row[2048 + dd], x2 = row[2048 + dd + 128];
    unsigned short* ko = Kf + ((size_t)b * TPAD_ + PRE_ + s) * HD_;
    ko[dd] = f2bf(x1 * cc - x2 * sn);
    ko[dd + 128] = f2bf(x2 * cc + x1 * sn);
  }
  Vt[((size_t)(b * HD_ + tid)) * TPAD_ + PRE_ + s] = f2bf(row[2304 + tid]);
}

// ---------------------------------------------------------------- all-layer prefix convert: K row-major, V transposed
__global__ __launch_bounds__(256) void prefixAll_k(const float* __restrict__ pk, const float* __restrict__ pv,
                                                   unsigned short* __restrict__ Kf_all,
                                                   unsigned short* __restrict__ Vt_all) {
  int b = blockIdx.y, t0 = blockIdx.x * 64, layer = blockIdx.z, tid = threadIdx.x;
  unsigned short* Kf = Kf_all + (size_t)layer * B_ * TPAD_ * HD_;
  unsigned short* Vt = Vt_all + (size_t)layer * B_ * HD_ * TPAD_;
  __shared__ unsigned short vt[256][72];
  const float* kp = pk + ((size_t)(b * L_ + layer)) * PRE_ * HD_;
  const float* vp = pv + ((size_t)(b * L_ + layer)) * PRE_ * HD_;
  for (int i = 0; i < 64; i++) {
    int t = t0 + i;
    float kv = 0.f, vv = 0.f;
    if (t < PRE_) {
      kv = kp[(size_t)t * HD_ + tid];
      vv = vp[(size_t)t * HD_ + tid];
    }
    Kf[((size_t)b * TPAD_ + t) * HD_ + tid] = f2bf(kv);  // suffix rows overwritten by qkvRR later
    vt[tid][i] = f2bf(vv);
  }
  __syncthreads();
#pragma unroll
  for (int p = 0; p < 4; p++) {
    int d = p * 64 + (tid >> 2);
    int c0 = (tid & 3) * 16;
    u16x8 v0, v1;
#pragma unroll
    for (int j = 0; j < 8; j++) { v0[j] = vt[d][c0 + j]; v1[j] = vt[d][c0 + 8 + j]; }
    size_t dst = ((size_t)(b * HD_ + d)) * TPAD_ + t0 + c0;
    *(u16x8*)(Vt + dst) = v0;
    *(u16x8*)(Vt + dst + 8) = v1;
  }
}

// ---------------------------------------------------------------- FUSED flash attention: one kernel -> attb
// grid (4 row-groups, NH, B), 256 thr = 4 waves. Wave w handles KV chunk [w*256, w*256+256);
// all waves share the same 16 q-rows (rg*16..+16). Block-level combine in LDS.
__global__ __launch_bounds__(256) void flashF_k(const unsigned short* __restrict__ qr,
                                                const unsigned short* __restrict__ Kf,
                                                const unsigned short* __restrict__ Vt,
                                                unsigned short* __restrict__ attb) {
  const int rg = blockIdx.x, h = blockIdx.y, b = blockIdx.z;
  const int bh = b * NH_ + h;
  const int tid = threadIdx.x, w = tid >> 6, l = tid & 63;
  const int lr = l & 15, kg = l >> 4;
  const int t0 = w * 256;

  __shared__ union {
    unsigned short P[4][16][264];                       // per-wave P tiles (bf16)
    struct { float O[4][16][256]; float ml[4][16][2]; } c;  // combine buffers
  } sm;

  // ---- QK^T: 16 q-rows x 256 t (this wave's chunk)
  f32x4 sc[16];
#pragma unroll
  for (int nf = 0; nf < 16; nf++) sc[nf] = (f32x4){0.f, 0.f, 0.f, 0.f};
  const unsigned short* qbase = qr + ((size_t)bh * QROWS_ + rg * 16 + lr) * HD_;
  const unsigned short* kbase = Kf + ((size_t)b * TPAD_ + t0 + lr) * HD_;
#pragma unroll
  for (int k0 = 0; k0 < HD_; k0 += 32) {
    s16x8 a = *(const s16x8*)(qbase + k0 + 8 * kg);
#pragma unroll
    for (int nf = 0; nf < 16; nf++) {
      s16x8 bv = *(const s16x8*)(kbase + (size_t)nf * 16 * HD_ + k0 + 8 * kg);
      sc[nf] = __builtin_amdgcn_mfma_f32_16x16x32_bf16(a, bv, sc[nf], 0, 0, 0);
    }
  }
  // ---- scale + mask + chunk softmax (in regs; rows = rg*16 + 4*kg + r)
  float mx[4] = {-3.0e38f, -3.0e38f, -3.0e38f, -3.0e38f};
#pragma unroll
  for (int nf = 0; nf < 16; nf++) {
    int t = t0 + nf * 16 + lr;
#pragma unroll
    for (int r = 0; r < 4; r++) {
      int row = rg * 16 + 4 * kg + r;
      float v = sc[nf][r] * 0.0625f;
      if (t >= PRE_ && (t - PRE_) > row) v = -1e9f;
      sc[nf][r] = v;
      mx[r] = fmaxf(mx[r], v);
    }
  }
#pragma unroll
  for (int o = 8; o > 0; o >>= 1)
#pragma unroll
    for (int r = 0; r < 4; r++) mx[r] = fmaxf(mx[r], __shfl_xor(mx[r], o));
  float ls[4] = {0.f, 0.f, 0.f, 0.f};
#pragma unroll
  for (int nf = 0; nf < 16; nf++)
#pragma unroll
    for (int r = 0; r < 4; r++) {
      float p = expf(sc[nf][r] - mx[r]);
      sc[nf][r] = p;
      ls[r] += p;
    }
#pragma unroll
  for (int o = 8; o > 0; o >>= 1)
#pragma unroll
    for (int r = 0; r < 4; r++) ls[r] += __shfl_xor(ls[r], o);
  // ---- P -> LDS (bf16) [own-wave tile]
#pragma unroll
  for (int nf = 0; nf < 16; nf++)
#pragma unroll
    for (int r = 0; r < 4; r++) sm.P[w][4 * kg + r][nf * 16 + lr] = f2bf(sc[nf][r]);
  __syncthreads();
  // ---- PV (unnormalized): O[16 rows][256 d]
  f32x4 o4[16];
#pragma unroll
  for (int nf = 0; nf < 16; nf++) o4[nf] = (f32x4){0.f, 0.f, 0.f, 0.f};
  const unsigned short* vbase = Vt + ((size_t)(b * HD_ + lr)) * TPAD_ + t0;
#pragma unroll
  for (int ti = 0; ti < 256; ti += 32) {
    s16x8 a = *(const s16x8*)&sm.P[w][lr][ti + 8 * kg];
#pragma unroll
    for (int nf = 0; nf < 16; nf++) {
      s16x8 bv = *(const s16x8*)(vbase + (size_t)nf * 16 * TPAD_ + ti + 8 * kg);
      o4[nf] = __builtin_amdgcn_mfma_f32_16x16x32_bf16(a, bv, o4[nf], 0, 0, 0);
    }
  }
  __syncthreads();   // P region dead; safe to overlay combine buffers
  // ---- stash per-wave O and (m,l)
#pragma unroll
  for (int nf = 0; nf < 16; nf++)
#pragma unroll
    for (int r = 0; r < 4; r++) sm.c.O[w][4 * kg + r][nf * 16 + lr] = o4[nf][r];
  if (lr == 0) {
#pragma unroll
    for (int r = 0; r < 4; r++) {
      sm.c.ml[w][4 * kg + r][0] = mx[r];
      sm.c.ml[w][4 * kg + r][1] = ls[r];
    }
  }
  __syncthreads();
  // ---- combine 4 chunks, write attb (valid rows only); d = tid
#pragma unroll
  for (int row = 0; row < 16; row++) {
    int s = rg * 16 + row;
    if (s >= HOR_) break;
    float M = -3.0e38f;
#pragma unroll
    for (int z = 0; z < 4; z++) M = fmaxf(M, sm.c.ml[z][row][0]);
    float den = 0.f, o = 0.f;
#pragma unroll
    for (int z = 0; z < 4; z++) {
      float wz = expf(sm.c.ml[z][row][0] - M);
      den += wz * sm.c.ml[z][row][1];
      o += wz * sm.c.O[z][row][tid];
    }
    attb[((size_t)(b * HOR_ + s)) * 2048 + h * HD_ + tid] = f2bf(o / den);
  }
}

// ---------------------------------------------------------------- out = normedF @ action_out_w + b
__global__ __launch_bounds__(256) void fout_k(const unsigned short* __restrict__ nf, const float* __restrict__ Wo,
                                              const float* __restrict__ bo, float* __restrict__ out) {
  int m = blockIdx.x, tid = threadIdx.x;
  int n = tid & 31, kg = tid >> 5;
  float acc = 0.f;
  for (int k = kg * 128; k < kg * 128 + 128; k++)
    acc += bf2f(nf[(size_t)m * H_ + k]) * Wo[(size_t)k * AD_ + n];
  __shared__ float red[8][32];
  red[kg][n] = acc;
  __syncthreads();
  if (kg == 0) {
    float v = 0.f;
#pragma unroll
    for (int g = 0; g < 8; g++) v += red[g][n];
    out[(size_t)m * AD_ + n] = v + bo[n];
  }
}

// ================================================================ host
extern "C" void kernel_launch(void* const* d_in, const int* in_sizes, int n_in,
                              void* d_out, int out_size, void* d_ws, size_t ws_size,
                              hipStream_t stream) {
  const float* prefix_keys   = (const float*)d_in[0];
  const float* prefix_values = (const float*)d_in[1];
  const float* x_t           = (const float*)d_in[2];
  const float* timestep      = (const float*)d_in[3];
  const unsigned char* pad_mask = (const unsigned char*)d_in[4];
  const float* action_in_w   = (const float*)d_in[5];
  const float* action_in_b   = (const float*)d_in[6];
  const float* action_out_w  = (const float*)d_in[7];
  const float* action_out_b  = (const float*)d_in[8];
  const float* tmlp_in_w     = (const float*)d_in[9];
  const float* tmlp_in_b     = (const float*)d_in[10];
  const float* tmlp_out_w    = (const float*)d_in[11];
  const float* tmlp_out_b    = (const float*)d_in[12];
  const float* w_q    = (const float*)d_in[13];
  const float* w_k    = (const float*)d_in[14];
  const float* w_v    = (const float*)d_in[15];
  const float* w_o    = (const float*)d_in[16];
  const float* w_gate = (const float*)d_in[17];
  const float* w_up   = (const float*)d_in[18];
  const float* w_down = (const float*)d_in[19];
  const float* in_norm_w    = (const float*)d_in[20];
  const float* in_scale_w   = (const float*)d_in[21];
  const float* in_gate_w    = (const float*)d_in[22];
  const float* post_norm_w  = (const float*)d_in[23];
  const float* post_scale_w = (const float*)d_in[24];
  const float* post_gate_w  = (const float*)d_in[25];
  const float* fnorm_w       = (const float*)d_in[26];
  const float* fnorm_scale_w = (const float*)d_in[27];

  char* wsp = (char*)d_ws;
  auto alloc = [&](size_t bytes) { void* p = (void*)wsp; wsp += (bytes + 255) & ~(size_t)255; return p; };

  float* emb0   = (float*)alloc((size_t)8 * H_ * 4);
  float* emb1   = (float*)alloc((size_t)8 * H_ * 4);
  float* cond   = (float*)alloc((size_t)8 * H_ * 4);
  float* fscale = (float*)alloc((size_t)8 * H_ * 4);
  float* gates  = (float*)alloc((size_t)4 * L_ * 8 * H_ * 4);
  int*   offs   = (int*)alloc(64);
  float* hbuf   = (float*)alloc((size_t)MPAD_ * H_ * 4);
  float* h1buf  = (float*)alloc((size_t)MPAD_ * H_ * 4);
  unsigned short* normed  = (unsigned short*)alloc((size_t)MPAD_ * H_ * 2);
  unsigned short* normed2 = (unsigned short*)alloc((size_t)MPAD_ * H_ * 2);
  unsigned short* q_r     = (unsigned short*)alloc((size_t)B_ * NH_ * QROWS_ * HD_ * 2);
  unsigned short* Kf_all  = (unsigned short*)alloc((size_t)L_ * B_ * TPAD_ * HD_ * 2);
  unsigned short* Vt_all  = (unsigned short*)alloc((size_t)L_ * B_ * HD_ * TPAD_ * 2);
  unsigned short* attb    = (unsigned short*)alloc((size_t)MPAD_ * 2048 * 2);
  unsigned short* t_buf   = (unsigned short*)alloc((size_t)MPAD_ * FF_ * 2);
  float* qkvpart = (float*)alloc((size_t)2 * MPAD_ * 2560 * 4);
  float* wopart  = (float*)alloc((size_t)4 * MPAD_ * 1024 * 4);
  float* dpart   = (float*)alloc((size_t)4 * MPAD_ * 1024 * 4);

  // attb pad rows (400..511) are never written by flashF_k: zero once (stays zero all layers)
  hipMemsetAsync(attb + (size_t)MROWS_ * 2048, 0, (size_t)(MPAD_ - MROWS_) * 2048 * 2, stream);

  emb_k<<<8, 256, 0, stream>>>(timestep, emb0);
  gemm8_k<<<16, 256, 0, stream>>>(emb0, tmlp_in_w, tmlp_in_b, emb1, 1);
  gemm8_k<<<16, 256, 0, stream>>>(emb1, tmlp_out_w, tmlp_out_b, cond, 1);
  gemm8_k<<<16, 256, 0, stream>>>(cond, fnorm_scale_w, nullptr, fscale, 0);
  gates_k<<<dim3(16, L_, 4), 256, 0, stream>>>(cond, in_scale_w, in_gate_w, post_scale_w, post_gate_w, gates);
  offs_k<<<1, 256, 0, stream>>>(pad_mask, offs);
  action_in_k<<<(MPAD_ * H_) / 256, 256, 0, stream>>>(x_t, action_in_w, action_in_b, hbuf);
  prefixAll_k<<<dim3(16, B_, L_), 256, 0, stream>>>(prefix_keys, prefix_values, Kf_all, Vt_all);
  ada_k<<<MPAD_, 256, 0, stream>>>(hbuf, in_norm_w, gates + 0, normed);  // layer 0 in_scale = gates[0][0]

  for (int i = 0; i < L_; i++) {
    const float* wq_i = w_q + (size_t)i * H_ * 2048;
    const float* wk_i = w_k + (size_t)i * H_ * HD_;
    const float* wv_i = w_v + (size_t)i * H_ * HD_;
    const float* wo_i = w_o + (size_t)i * 2048 * H_;
    const float* wg_i = w_gate + (size_t)i * H_ * FF_;
    const float* wu_i = w_up + (size_t)i * H_ * FF_;
    const float* wd_i = w_down + (size_t)i * FF_ * H_;
    const float* g_in_gate    = gates + ((size_t)(1 * L_ + i) * 8) * H_;
    const float* g_post_scale = gates + ((size_t)(2 * L_ + i) * 8) * H_;
    const float* g_post_gate  = gates + ((size_t)(3 * L_ + i) * 8) * H_;
    unsigned short* Kf_l = Kf_all + (size_t)i * B_ * TPAD_ * HD_;
    unsigned short* Vt_l = Vt_all + (size_t)i * B_ * HD_ * TPAD_;

    gemmS_k<0, 2, 2><<<dim3(80, 2, 2), 512, 0, stream>>>(normed, H_, H_, wq_i, wk_i, wv_i, qkvpart, nullptr);
    qkvRR_k<<<dim3(QROWS_, B_), 256, 0, stream>>>(qkvpart, offs, q_r, Kf_l, Vt_l);
    flashF_k<<<dim3(4, NH_, B_), 256, 0, stream>>>(q_r, Kf_l, Vt_l, attb);
    gemmS_k<1, 4, 2><<<dim3(32, 4, 2), 512, 0, stream>>>(attb, 2048, 2048, wo_i, nullptr, nullptr, wopart, nullptr);
    redA_k<4><<<MPAD_, 256, 0, stream>>>(wopart, hbuf, g_in_gate, post_norm_w + (size_t)i * H_,
                                         g_post_scale, h1buf, normed2);
    gemmS_k<2, 1, 2><<<dim3(128, 1, 2), 512, 0, stream>>>(normed2, H_, H_, wg_i, wu_i, nullptr, nullptr, t_buf);
    gemmS_k<3, 4, 2><<<dim3(32, 4, 2), 512, 0, stream>>>(t_buf, FF_, FF_, wd_i, nullptr, nullptr, dpart, nullptr);
    const float* nw_next = (i + 1 < L_) ? in_norm_w + (size_t)(i + 1) * H_ : fnorm_w;
    const float* sc_next = (i + 1 < L_) ? gates + ((size_t)(0 * L_ + i + 1) * 8) * H_ : fscale;
    redA_k<4><<<MPAD_, 256, 0, stream>>>(dpart, h1buf, g_post_gate, nw_next, sc_next, hbuf, normed);
  }

  fout_k<<<MROWS_, 256, 0, stream>>>(normed, action_out_w, action_out_b, (float*)d_out);
}